// Round 1
// baseline (8261.331 us; speedup 1.0000x reference)
//
#include <hip/hip_runtime.h>
#include <math.h>

#define NN 50000
#define NE 1600000
#define D 64
#define DE 32
#define H 4
#define DH 16
#define L 3

__device__ __forceinline__ void atomicMaxFloat(float* addr, float val) {
    if (val >= 0.f) atomicMax((int*)addr, __float_as_int(val));
    else atomicMin((unsigned int*)addr, __float_as_uint(val));
}

// ---- init per-layer scratch: m=-inf, denom=0, agg=0 ----
__global__ void init_kernel(float* __restrict__ m, float* __restrict__ denom,
                            float* __restrict__ agg) {
    int t = blockIdx.x * 256 + threadIdx.x;
    if (t < NN * H) { m[t] = -INFINITY; denom[t] = 0.f; }
    if (t < NN * D) agg[t] = 0.f;
}

// ---- q,k,v = h @ {Wq,Wk,Wv} ----
__global__ void qkv_kernel(const float* __restrict__ h,
                           const float* __restrict__ Wq,
                           const float* __restrict__ Wk,
                           const float* __restrict__ Wv,
                           float* __restrict__ q, float* __restrict__ k,
                           float* __restrict__ v) {
    __shared__ float sWq[D * D], sWk[D * D], sWv[D * D];
    __shared__ float sh[4][D];
    int col = threadIdx.x;          // 0..63
    int r = threadIdx.y;            // 0..3
    int tid = r * 64 + col;
    for (int i = tid; i < D * D; i += 256) {
        sWq[i] = Wq[i]; sWk[i] = Wk[i]; sWv[i] = Wv[i];
    }
    int node = blockIdx.x * 4 + r;
    if (node < NN) sh[r][col] = h[node * D + col];
    __syncthreads();
    if (node >= NN) return;
    float aq = 0.f, ak = 0.f, av = 0.f;
#pragma unroll
    for (int kk = 0; kk < D; kk++) {
        float hv = sh[r][kk];
        aq += hv * sWq[kk * D + col];
        ak += hv * sWk[kk * D + col];
        av += hv * sWv[kk * D + col];
    }
    q[node * D + col] = aq;
    k[node * D + col] = ak;
    v[node * D + col] = av;
}

// ---- scores = (q[dst].k[src])/sqrt(dh) + e@We ; segment max into m ----
__global__ void score_kernel(const float* __restrict__ q, const float* __restrict__ k,
                             const float* __restrict__ e,
                             const int* __restrict__ src, const int* __restrict__ dst,
                             const float* __restrict__ We,  // DE x H
                             float* __restrict__ scores, float* __restrict__ m) {
    int t = blockIdx.x * 256 + threadIdx.x;
    if (t >= NE * H) return;
    int edge = t >> 2;
    int hh = t & 3;
    int s = src[edge], d0 = dst[edge];
    const float4* qp = (const float4*)(q + d0 * D + hh * DH);
    const float4* kp = (const float4*)(k + s * D + hh * DH);
    float acc = 0.f;
#pragma unroll
    for (int i = 0; i < 4; i++) {
        float4 a = qp[i], b = kp[i];
        acc += a.x * b.x + a.y * b.y + a.z * b.z + a.w * b.w;
    }
    acc *= 0.25f;  // 1/sqrt(16)
    const float* ep = e + (size_t)edge * DE;
    float bias = 0.f;
#pragma unroll
    for (int i = 0; i < DE; i++) bias += ep[i] * We[i * H + hh];
    acc += bias;
    scores[t] = acc;
    atomicMaxFloat(&m[d0 * H + hh], acc);
}

// ---- p = exp(s - m[dst]) ; segment sum into denom ----
__global__ void exp_kernel(const int* __restrict__ dst, const float* __restrict__ m,
                           float* __restrict__ scores, float* __restrict__ denom) {
    int t = blockIdx.x * 256 + threadIdx.x;
    if (t >= NE * H) return;
    int edge = t >> 2;
    int hh = t & 3;
    int d0 = dst[edge];
    float p = expf(scores[t] - m[d0 * H + hh]);
    scores[t] = p;
    atomicAdd(&denom[d0 * H + hh], p);
}

// ---- agg[dst] += alpha * v[src] ; 16 threads/edge, 4 cols each ----
__global__ void agg_kernel(const float* __restrict__ v, const float* __restrict__ p,
                           const float* __restrict__ denom,
                           const int* __restrict__ src, const int* __restrict__ dst,
                           float* __restrict__ agg) {
    int t = blockIdx.x * 256 + threadIdx.x;
    if (t >= NE * 16) return;
    int edge = t >> 4;
    int g = t & 15;      // col group: cols 4g..4g+3
    int hh = g >> 2;
    int s = src[edge], d0 = dst[edge];
    float alpha = p[edge * H + hh] / (denom[d0 * H + hh] + 1e-9f);
    float4 vv = *(const float4*)(v + s * D + g * 4);
    float* ap = agg + d0 * D + g * 4;
    atomicAdd(ap + 0, alpha * vv.x);
    atomicAdd(ap + 1, alpha * vv.y);
    atomicAdd(ap + 2, alpha * vv.z);
    atomicAdd(ap + 3, alpha * vv.w);
}

// ---- h = LN(h + agg @ Wo) ----
__global__ void node_update_kernel(float* __restrict__ h, const float* __restrict__ agg,
                                   const float* __restrict__ Wo,
                                   const float* __restrict__ gn,
                                   const float* __restrict__ bn) {
    __shared__ float sWo[D * D];
    __shared__ float sagg[4][D];
    int col = threadIdx.x, r = threadIdx.y;
    int tid = r * 64 + col;
    for (int i = tid; i < D * D; i += 256) sWo[i] = Wo[i];
    int node = blockIdx.x * 4 + r;
    if (node < NN) sagg[r][col] = agg[node * D + col];
    __syncthreads();
    if (node >= NN) return;
    float acc = 0.f;
#pragma unroll
    for (int kk = 0; kk < D; kk++) acc += sagg[r][kk] * sWo[kk * D + col];
    float x = h[node * D + col] + acc;
    float sum = x, sq = x * x;
#pragma unroll
    for (int off = 32; off; off >>= 1) {
        sum += __shfl_xor(sum, off);
        sq += __shfl_xor(sq, off);
    }
    float mu = sum * (1.f / 64.f);
    float var = sq * (1.f / 64.f) - mu * mu;
    float out = (x - mu) * rsqrtf(var + 1e-5f) * gn[col] + bn[col];
    h[node * D + col] = out;
}

// ---- e = LN(e + gelu(concat(h[src],h[dst],e) @ Wem + bem)) ----
__global__ void edge_update_kernel(const float* __restrict__ h, float* __restrict__ e,
                                   const int* __restrict__ src, const int* __restrict__ dst,
                                   const float* __restrict__ Wem,  // 160 x 32
                                   const float* __restrict__ bem,
                                   const float* __restrict__ ge,
                                   const float* __restrict__ be) {
    __shared__ float sW[160 * 32];   // 20 KB
    __shared__ float sx[8][160];
    int tid = threadIdx.x;           // 0..255
    for (int i = tid; i < 160 * 32; i += 256) sW[i] = Wem[i];
    int le = tid >> 5;               // local edge 0..7
    int j = tid & 31;                // out col 0..31
    int edge = blockIdx.x * 8 + le;
    float eold = 0.f;
    if (edge < NE) {
        int s = src[edge], d0 = dst[edge];
        sx[le][j] = h[s * D + j];
        sx[le][j + 32] = h[s * D + 32 + j];
        sx[le][j + 64] = h[d0 * D + j];
        sx[le][j + 96] = h[d0 * D + 32 + j];
        eold = e[(size_t)edge * DE + j];
        sx[le][j + 128] = eold;
    }
    __syncthreads();
    if (edge >= NE) return;
    float acc = bem[j];
#pragma unroll
    for (int kk = 0; kk < 160; kk++) acc += sx[le][kk] * sW[kk * 32 + j];
    // gelu (tanh approximation, jax.nn.gelu default)
    float u = 0.7978845608028654f * (acc + 0.044715f * acc * acc * acc);
    float g = 0.5f * acc * (1.f + tanhf(u));
    float y = eold + g;
    float sum = y, sq = y * y;
#pragma unroll
    for (int off = 16; off; off >>= 1) {
        sum += __shfl_xor(sum, off, 32);
        sq += __shfl_xor(sq, off, 32);
    }
    float mu = sum * (1.f / 32.f);
    float var = sq * (1.f / 32.f) - mu * mu;
    e[(size_t)edge * DE + j] = (y - mu) * rsqrtf(var + 1e-5f) * ge[j] + be[j];
}

extern "C" void kernel_launch(void* const* d_in, const int* in_sizes, int n_in,
                              void* d_out, int out_size, void* d_ws, size_t ws_size,
                              hipStream_t stream) {
    const float* node_features = (const float*)d_in[0];
    float* e = (float*)d_in[1];     // updated in place; harness restores inputs
    const int* edge_index = (const int*)d_in[2];
    const int* src = edge_index;
    const int* dst = edge_index + NE;
    const float* Wq = (const float*)d_in[3];
    const float* Wk = (const float*)d_in[4];
    const float* Wv = (const float*)d_in[5];
    const float* Wo = (const float*)d_in[6];
    const float* We = (const float*)d_in[7];
    const float* Wem = (const float*)d_in[8];
    const float* bem = (const float*)d_in[9];
    const float* gn = (const float*)d_in[10];
    const float* bn = (const float*)d_in[11];
    const float* ge = (const float*)d_in[12];
    const float* be = (const float*)d_in[13];

    float* h = (float*)d_out;       // h lives in d_out

    float* ws = (float*)d_ws;
    float* q = ws;                      // N*D
    float* k = q + NN * D;              // N*D
    float* v = k + NN * D;              // N*D
    float* agg = v + NN * D;            // N*D
    float* p = agg + NN * D;            // E*H
    float* m = p + (size_t)NE * H;      // N*H
    float* denom = m + NN * H;          // N*H

    hipMemcpyAsync(h, node_features, (size_t)NN * D * sizeof(float),
                   hipMemcpyDeviceToDevice, stream);

    for (int layer = 0; layer < L; layer++) {
        const float* Wq_l = Wq + layer * D * D;
        const float* Wk_l = Wk + layer * D * D;
        const float* Wv_l = Wv + layer * D * D;
        const float* Wo_l = Wo + layer * D * D;
        const float* We_l = We + layer * DE * H;
        const float* Wem_l = Wem + layer * (2 * D + DE) * DE;
        const float* bem_l = bem + layer * DE;
        const float* gn_l = gn + layer * D;
        const float* bn_l = bn + layer * D;
        const float* ge_l = ge + layer * DE;
        const float* be_l = be + layer * DE;

        init_kernel<<<(NN * D + 255) / 256, 256, 0, stream>>>(m, denom, agg);
        qkv_kernel<<<(NN + 3) / 4, dim3(64, 4), 0, stream>>>(h, Wq_l, Wk_l, Wv_l, q, k, v);
        score_kernel<<<(NE * H + 255) / 256, 256, 0, stream>>>(q, k, e, src, dst, We_l, p, m);
        exp_kernel<<<(NE * H + 255) / 256, 256, 0, stream>>>(dst, m, p, denom);
        agg_kernel<<<(NE * 16 + 255) / 256, 256, 0, stream>>>(v, p, denom, src, dst, agg);
        node_update_kernel<<<(NN + 3) / 4, dim3(64, 4), 0, stream>>>(h, agg, Wo_l, gn_l, bn_l);
        edge_update_kernel<<<(NE + 7) / 8, 256, 0, stream>>>(h, e, src, dst, Wem_l, bem_l, ge_l, be_l);
    }
}

// Round 2
// 4239.322 us; speedup vs baseline: 1.9487x; 1.9487x over previous
//
#include <hip/hip_runtime.h>
#include <math.h>

#define NN 50000
#define NE 1600000
#define D 64
#define DE 32
#define H 4
#define DH 16
#define L 3

// ======================= CSR build (per launch) =======================

__global__ void deg_kernel(const int* __restrict__ dst, int* __restrict__ cnt) {
    int e = blockIdx.x * 256 + threadIdx.x;
    if (e >= NE) return;
    atomicAdd(&cnt[dst[e]], 1);
}

// each block sums a 1024-chunk of cnt
__global__ void block_sum_kernel(const int* __restrict__ cnt, int* __restrict__ bsum) {
    int b = blockIdx.x, t = threadIdx.x;
    int base = b * 1024 + t * 4;
    int s = 0;
#pragma unroll
    for (int i = 0; i < 4; i++) { int idx = base + i; if (idx < NN) s += cnt[idx]; }
#pragma unroll
    for (int off = 32; off; off >>= 1) s += __shfl_down(s, off);
    __shared__ int wsum[4];
    if ((t & 63) == 0) wsum[t >> 6] = s;
    __syncthreads();
    if (t == 0) bsum[b] = wsum[0] + wsum[1] + wsum[2] + wsum[3];
}

__global__ void scan_bsum_kernel(int* __restrict__ bsum, int nb) {
    if (blockIdx.x == 0 && threadIdx.x == 0) {
        int run = 0;
        for (int i = 0; i < nb; i++) { int c = bsum[i]; bsum[i] = run; run += c; }
    }
}

// per-block exclusive scan of cnt -> offsets, using bsum prefix
__global__ void scan_block_kernel(const int* __restrict__ cnt, const int* __restrict__ bsum,
                                  int* __restrict__ offsets) {
    int b = blockIdx.x, t = threadIdx.x;
    int base = b * 1024 + t * 4;
    int v[4]; int s = 0;
#pragma unroll
    for (int i = 0; i < 4; i++) { int idx = base + i; v[i] = (idx < NN) ? cnt[idx] : 0; s += v[i]; }
    int lane = t & 63, w = t >> 6;
    int x = s;
#pragma unroll
    for (int off = 1; off < 64; off <<= 1) {
        int y = __shfl_up(x, off);
        if (lane >= off) x += y;
    }
    __shared__ int wsum[4];
    if (lane == 63) wsum[w] = x;
    __syncthreads();
    int woff = 0;
    for (int i = 0; i < w; i++) woff += wsum[i];
    int run = bsum[b] + woff + x - s;   // exclusive prefix for this thread
#pragma unroll
    for (int i = 0; i < 4; i++) {
        int idx = base + i;
        if (idx < NN) offsets[idx] = run;
        run += v[i];
    }
}

__global__ void scatter_kernel(const int* __restrict__ dst, const int* __restrict__ offsets,
                               int* __restrict__ cursor, int* __restrict__ sorted_eid) {
    int e = blockIdx.x * 256 + threadIdx.x;
    if (e >= NE) return;
    int d0 = dst[e];
    int pos = atomicAdd(&cursor[d0], 1);
    sorted_eid[offsets[d0] + pos] = e;
}

// ======================= per-layer kernels =======================

// ---- q,k,v = h @ {Wq,Wk,Wv} ----
__global__ void qkv_kernel(const float* __restrict__ h,
                           const float* __restrict__ Wq,
                           const float* __restrict__ Wk,
                           const float* __restrict__ Wv,
                           float* __restrict__ q, float* __restrict__ k,
                           float* __restrict__ v) {
    __shared__ float sWq[D * D], sWk[D * D], sWv[D * D];
    __shared__ float sh[4][D];
    int col = threadIdx.x;          // 0..63
    int r = threadIdx.y;            // 0..3
    int tid = r * 64 + col;
    for (int i = tid; i < D * D; i += 256) {
        sWq[i] = Wq[i]; sWk[i] = Wk[i]; sWv[i] = Wv[i];
    }
    int node = blockIdx.x * 4 + r;
    if (node < NN) sh[r][col] = h[node * D + col];
    __syncthreads();
    if (node >= NN) return;
    float aq = 0.f, ak = 0.f, av = 0.f;
#pragma unroll
    for (int kk = 0; kk < D; kk++) {
        float hv = sh[r][kk];
        aq += hv * sWq[kk * D + col];
        ak += hv * sWk[kk * D + col];
        av += hv * sWv[kk * D + col];
    }
    q[node * D + col] = aq;
    k[node * D + col] = ak;
    v[node * D + col] = av;
}

// ---- ebias[e,h] = e_row . We[:,h] ----
__global__ void ebias_kernel(const float* __restrict__ e, const float* __restrict__ We,
                             float* __restrict__ ebias) {
    int t = blockIdx.x * 256 + threadIdx.x;
    if (t >= NE * H) return;
    int edge = t >> 2;
    int hh = t & 3;
    const float* ep = e + (size_t)edge * DE;
    float bias = 0.f;
#pragma unroll
    for (int i = 0; i < DE; i++) bias += ep[i] * We[i * H + hh];
    ebias[t] = bias;
}

// ---- fused: per-dst-node online-softmax attention + aggregation (no atomics) ----
__global__ void attn_kernel(const float* __restrict__ q, const float* __restrict__ k,
                            const float* __restrict__ v,
                            const float* __restrict__ ebias,
                            const int* __restrict__ src,
                            const int* __restrict__ offsets,
                            const int* __restrict__ sorted_eid,
                            float* __restrict__ agg) {
    int node = blockIdx.x * 4 + threadIdx.y;
    if (node >= NN) return;
    int lane = threadIdx.x;        // 0..63 = output column
    int hh = lane >> 4;            // head for this column
    float qv = q[node * D + lane] * 0.25f;   // fold 1/sqrt(16)
    int beg = offsets[node];
    int end = (node == NN - 1) ? NE : offsets[node + 1];
    float mmax = -INFINITY, den = 0.f, acc = 0.f;
    for (int i = beg; i < end; i++) {
        int e = sorted_eid[i];
        int s = src[e];
        float kv = k[s * D + lane];
        float vv = v[s * D + lane];
        float dot = qv * kv;
        // reduce within each 16-lane head group
#pragma unroll
        for (int off = 1; off < 16; off <<= 1) dot += __shfl_xor(dot, off, 16);
        float score = dot + ebias[e * H + hh];
        float nm = fmaxf(mmax, score);
        float scale = __expf(mmax - nm);   // first iter: exp(-inf)=0
        float p = __expf(score - nm);
        den = den * scale + p;
        acc = acc * scale + p * vv;
        mmax = nm;
    }
    agg[node * D + lane] = acc / (den + 1e-9f);
}

// ---- h = LN(h + agg @ Wo) ----
__global__ void node_update_kernel(float* __restrict__ h, const float* __restrict__ agg,
                                   const float* __restrict__ Wo,
                                   const float* __restrict__ gn,
                                   const float* __restrict__ bn) {
    __shared__ float sWo[D * D];
    __shared__ float sagg[4][D];
    int col = threadIdx.x, r = threadIdx.y;
    int tid = r * 64 + col;
    for (int i = tid; i < D * D; i += 256) sWo[i] = Wo[i];
    int node = blockIdx.x * 4 + r;
    if (node < NN) sagg[r][col] = agg[node * D + col];
    __syncthreads();
    if (node >= NN) return;
    float acc = 0.f;
#pragma unroll
    for (int kk = 0; kk < D; kk++) acc += sagg[r][kk] * sWo[kk * D + col];
    float x = h[node * D + col] + acc;
    float sum = x, sq = x * x;
#pragma unroll
    for (int off = 32; off; off >>= 1) {
        sum += __shfl_xor(sum, off);
        sq += __shfl_xor(sq, off);
    }
    float mu = sum * (1.f / 64.f);
    float var = sq * (1.f / 64.f) - mu * mu;
    float out = (x - mu) * rsqrtf(var + 1e-5f) * gn[col] + bn[col];
    h[node * D + col] = out;
}

// ---- e = LN(e + gelu(concat(h[src],h[dst],e) @ Wem + bem)) ----
__global__ void edge_update_kernel(const float* __restrict__ h, float* __restrict__ e,
                                   const int* __restrict__ src, const int* __restrict__ dst,
                                   const float* __restrict__ Wem,  // 160 x 32
                                   const float* __restrict__ bem,
                                   const float* __restrict__ ge,
                                   const float* __restrict__ be) {
    __shared__ float sW[160 * 32];   // 20 KB
    __shared__ float sx[8][160];
    int tid = threadIdx.x;           // 0..255
    for (int i = tid; i < 160 * 32; i += 256) sW[i] = Wem[i];
    int le = tid >> 5;               // local edge 0..7
    int j = tid & 31;                // out col 0..31
    int edge = blockIdx.x * 8 + le;
    float eold = 0.f;
    if (edge < NE) {
        int s = src[edge], d0 = dst[edge];
        sx[le][j] = h[s * D + j];
        sx[le][j + 32] = h[s * D + 32 + j];
        sx[le][j + 64] = h[d0 * D + j];
        sx[le][j + 96] = h[d0 * D + 32 + j];
        eold = e[(size_t)edge * DE + j];
        sx[le][j + 128] = eold;
    }
    __syncthreads();
    if (edge >= NE) return;
    float acc = bem[j];
#pragma unroll
    for (int kk = 0; kk < 160; kk++) acc += sx[le][kk] * sW[kk * 32 + j];
    // gelu (tanh approximation, jax.nn.gelu default)
    float u = 0.7978845608028654f * (acc + 0.044715f * acc * acc * acc);
    float g = 0.5f * acc * (1.f + tanhf(u));
    float y = eold + g;
    float sum = y, sq = y * y;
#pragma unroll
    for (int off = 16; off; off >>= 1) {
        sum += __shfl_xor(sum, off, 32);
        sq += __shfl_xor(sq, off, 32);
    }
    float mu = sum * (1.f / 32.f);
    float var = sq * (1.f / 32.f) - mu * mu;
    e[(size_t)edge * DE + j] = (y - mu) * rsqrtf(var + 1e-5f) * ge[j] + be[j];
}

extern "C" void kernel_launch(void* const* d_in, const int* in_sizes, int n_in,
                              void* d_out, int out_size, void* d_ws, size_t ws_size,
                              hipStream_t stream) {
    const float* node_features = (const float*)d_in[0];
    float* e = (float*)d_in[1];     // updated in place; harness restores inputs
    const int* edge_index = (const int*)d_in[2];
    const int* src = edge_index;
    const int* dst = edge_index + NE;
    const float* Wq = (const float*)d_in[3];
    const float* Wk = (const float*)d_in[4];
    const float* Wv = (const float*)d_in[5];
    const float* Wo = (const float*)d_in[6];
    const float* We = (const float*)d_in[7];
    const float* Wem = (const float*)d_in[8];
    const float* bem = (const float*)d_in[9];
    const float* gn = (const float*)d_in[10];
    const float* bn = (const float*)d_in[11];
    const float* ge = (const float*)d_in[12];
    const float* be = (const float*)d_in[13];

    float* h = (float*)d_out;       // h lives in d_out

    float* ws = (float*)d_ws;
    float* q = ws;                                   // N*D
    float* k = q + NN * D;                           // N*D
    float* v = k + NN * D;                           // N*D
    float* agg = v + NN * D;                         // N*D
    float* ebias = agg + NN * D;                     // E*H
    int* offsets = (int*)(ebias + (size_t)NE * H);   // NN
    int* cursor = offsets + NN;                      // NN (also degree counts)
    int* bsum = cursor + NN;                         // 64
    int* sorted_eid = bsum + 64;                     // NE

    const int NB = (NN + 1023) / 1024;               // 49 scan blocks

    // ---- CSR build (edge_index is constant; rebuilt every launch) ----
    hipMemsetAsync(cursor, 0, NN * sizeof(int), stream);
    deg_kernel<<<(NE + 255) / 256, 256, 0, stream>>>(dst, cursor);
    block_sum_kernel<<<NB, 256, 0, stream>>>(cursor, bsum);
    scan_bsum_kernel<<<1, 64, 0, stream>>>(bsum, NB);
    scan_block_kernel<<<NB, 256, 0, stream>>>(cursor, bsum, offsets);
    hipMemsetAsync(cursor, 0, NN * sizeof(int), stream);
    scatter_kernel<<<(NE + 255) / 256, 256, 0, stream>>>(dst, offsets, cursor, sorted_eid);

    hipMemcpyAsync(h, node_features, (size_t)NN * D * sizeof(float),
                   hipMemcpyDeviceToDevice, stream);

    for (int layer = 0; layer < L; layer++) {
        const float* Wq_l = Wq + layer * D * D;
        const float* Wk_l = Wk + layer * D * D;
        const float* Wv_l = Wv + layer * D * D;
        const float* Wo_l = Wo + layer * D * D;
        const float* We_l = We + layer * DE * H;
        const float* Wem_l = Wem + layer * (2 * D + DE) * DE;
        const float* bem_l = bem + layer * DE;
        const float* gn_l = gn + layer * D;
        const float* bn_l = bn + layer * D;
        const float* ge_l = ge + layer * DE;
        const float* be_l = be + layer * DE;

        qkv_kernel<<<(NN + 3) / 4, dim3(64, 4), 0, stream>>>(h, Wq_l, Wk_l, Wv_l, q, k, v);
        ebias_kernel<<<(NE * H + 255) / 256, 256, 0, stream>>>(e, We_l, ebias);
        attn_kernel<<<(NN + 3) / 4, dim3(64, 4), 0, stream>>>(q, k, v, ebias, src,
                                                              offsets, sorted_eid, agg);
        node_update_kernel<<<(NN + 3) / 4, dim3(64, 4), 0, stream>>>(h, agg, Wo_l, gn_l, bn_l);
        edge_update_kernel<<<(NE + 7) / 8, 256, 0, stream>>>(h, e, src, dst, Wem_l, bem_l, ge_l, be_l);
    }
}

// Round 3
// 2383.821 us; speedup vs baseline: 3.4656x; 1.7784x over previous
//
#include <hip/hip_runtime.h>
#include <hip/hip_bf16.h>
#include <math.h>

#define NN 50000
#define NE 1600000
#define D 64
#define DE 32
#define H 4
#define DH 16
#define L 3

typedef __attribute__((ext_vector_type(8))) short bf16x8;
typedef __attribute__((ext_vector_type(4))) float f32x4;

__device__ __forceinline__ short f2b(float f) {
    __hip_bfloat16 h = __float2bfloat16(f);
    short s;
    __builtin_memcpy(&s, &h, 2);
    return s;
}

// ======================= CSR build (per launch) =======================

__global__ void deg_kernel(const int* __restrict__ dst, int* __restrict__ cnt) {
    int e = blockIdx.x * 256 + threadIdx.x;
    if (e >= NE) return;
    atomicAdd(&cnt[dst[e]], 1);
}

__global__ void block_sum_kernel(const int* __restrict__ cnt, int* __restrict__ bsum) {
    int b = blockIdx.x, t = threadIdx.x;
    int base = b * 1024 + t * 4;
    int s = 0;
#pragma unroll
    for (int i = 0; i < 4; i++) { int idx = base + i; if (idx < NN) s += cnt[idx]; }
#pragma unroll
    for (int off = 32; off; off >>= 1) s += __shfl_down(s, off);
    __shared__ int wsum[4];
    if ((t & 63) == 0) wsum[t >> 6] = s;
    __syncthreads();
    if (t == 0) bsum[b] = wsum[0] + wsum[1] + wsum[2] + wsum[3];
}

__global__ void scan_bsum_kernel(int* __restrict__ bsum, int nb) {
    if (blockIdx.x == 0 && threadIdx.x == 0) {
        int run = 0;
        for (int i = 0; i < nb; i++) { int c = bsum[i]; bsum[i] = run; run += c; }
    }
}

__global__ void scan_block_kernel(const int* __restrict__ cnt, const int* __restrict__ bsum,
                                  int* __restrict__ offsets) {
    int b = blockIdx.x, t = threadIdx.x;
    int base = b * 1024 + t * 4;
    int v[4]; int s = 0;
#pragma unroll
    for (int i = 0; i < 4; i++) { int idx = base + i; v[i] = (idx < NN) ? cnt[idx] : 0; s += v[i]; }
    int lane = t & 63, w = t >> 6;
    int x = s;
#pragma unroll
    for (int off = 1; off < 64; off <<= 1) {
        int y = __shfl_up(x, off);
        if (lane >= off) x += y;
    }
    __shared__ int wsum[4];
    if (lane == 63) wsum[w] = x;
    __syncthreads();
    int woff = 0;
    for (int i = 0; i < w; i++) woff += wsum[i];
    int run = bsum[b] + woff + x - s;
#pragma unroll
    for (int i = 0; i < 4; i++) {
        int idx = base + i;
        if (idx < NN) offsets[idx] = run;
        run += v[i];
    }
}

__global__ void scatter_kernel(const int* __restrict__ dst, const int* __restrict__ offsets,
                               int* __restrict__ cursor, int* __restrict__ sorted_eid) {
    int e = blockIdx.x * 256 + threadIdx.x;
    if (e >= NE) return;
    int d0 = dst[e];
    int pos = atomicAdd(&cursor[d0], 1);
    sorted_eid[offsets[d0] + pos] = e;
}

// ---- Wem[L][160][32] fp32 -> Wt[L][32][160] bf16 (transposed, once per launch) ----
__global__ void wconv_kernel(const float* __restrict__ Wem, unsigned short* __restrict__ Wt) {
    int t = blockIdx.x * 256 + threadIdx.x;
    if (t >= L * 32 * 160) return;
    int l = t / 5120;
    int r = t % 5120;
    int n = r / 160;
    int k = r % 160;
    Wt[t] = (unsigned short)f2b(Wem[l * 5120 + k * 32 + n]);
}

// ======================= per-layer kernels =======================

// ---- q,k,v = h @ {Wq,Wk,Wv} ----
__global__ void qkv_kernel(const float* __restrict__ h,
                           const float* __restrict__ Wq,
                           const float* __restrict__ Wk,
                           const float* __restrict__ Wv,
                           float* __restrict__ q, float* __restrict__ k,
                           float* __restrict__ v) {
    __shared__ float sWq[D * D], sWk[D * D], sWv[D * D];
    __shared__ float sh[4][D];
    int col = threadIdx.x;
    int r = threadIdx.y;
    int tid = r * 64 + col;
    for (int i = tid; i < D * D; i += 256) {
        sWq[i] = Wq[i]; sWk[i] = Wk[i]; sWv[i] = Wv[i];
    }
    int node = blockIdx.x * 4 + r;
    if (node < NN) sh[r][col] = h[node * D + col];
    __syncthreads();
    if (node >= NN) return;
    float aq = 0.f, ak = 0.f, av = 0.f;
#pragma unroll
    for (int kk = 0; kk < D; kk++) {
        float hv = sh[r][kk];
        aq += hv * sWq[kk * D + col];
        ak += hv * sWk[kk * D + col];
        av += hv * sWv[kk * D + col];
    }
    q[node * D + col] = aq;
    k[node * D + col] = ak;
    v[node * D + col] = av;
}

// ---- ebias[e,h] = e_row . We[:,h] ----
__global__ void ebias_kernel(const float* __restrict__ e, const float* __restrict__ We,
                             float* __restrict__ ebias) {
    int t = blockIdx.x * 256 + threadIdx.x;
    if (t >= NE * H) return;
    int edge = t >> 2;
    int hh = t & 3;
    const float* ep = e + (size_t)edge * DE;
    float bias = 0.f;
#pragma unroll
    for (int i = 0; i < DE; i++) bias += ep[i] * We[i * H + hh];
    ebias[t] = bias;
}

// ---- fused per-dst-node online-softmax attention + aggregation ----
__global__ void attn_kernel(const float* __restrict__ q, const float* __restrict__ k,
                            const float* __restrict__ v,
                            const float* __restrict__ ebias,
                            const int* __restrict__ src,
                            const int* __restrict__ offsets,
                            const int* __restrict__ sorted_eid,
                            float* __restrict__ agg) {
    int node = blockIdx.x * 4 + threadIdx.y;
    if (node >= NN) return;
    int lane = threadIdx.x;
    int hh = lane >> 4;
    float qv = q[node * D + lane] * 0.25f;
    int beg = offsets[node];
    int end = (node == NN - 1) ? NE : offsets[node + 1];
    float mmax = -INFINITY, den = 0.f, acc = 0.f;
    for (int i = beg; i < end; i++) {
        int e = sorted_eid[i];
        int s = src[e];
        float kv = k[s * D + lane];
        float vv = v[s * D + lane];
        float dot = qv * kv;
#pragma unroll
        for (int off = 1; off < 16; off <<= 1) dot += __shfl_xor(dot, off, 16);
        float score = dot + ebias[e * H + hh];
        float nm = fmaxf(mmax, score);
        float scale = __expf(mmax - nm);
        float p = __expf(score - nm);
        den = den * scale + p;
        acc = acc * scale + p * vv;
        mmax = nm;
    }
    agg[node * D + lane] = acc / (den + 1e-9f);
}

// ---- h = LN(h + agg @ Wo) ----
__global__ void node_update_kernel(float* __restrict__ h, const float* __restrict__ agg,
                                   const float* __restrict__ Wo,
                                   const float* __restrict__ gn,
                                   const float* __restrict__ bn) {
    __shared__ float sWo[D * D];
    __shared__ float sagg[4][D];
    int col = threadIdx.x, r = threadIdx.y;
    int tid = r * 64 + col;
    for (int i = tid; i < D * D; i += 256) sWo[i] = Wo[i];
    int node = blockIdx.x * 4 + r;
    if (node < NN) sagg[r][col] = agg[node * D + col];
    __syncthreads();
    if (node >= NN) return;
    float acc = 0.f;
#pragma unroll
    for (int kk = 0; kk < D; kk++) acc += sagg[r][kk] * sWo[kk * D + col];
    float x = h[node * D + col] + acc;
    float sum = x, sq = x * x;
#pragma unroll
    for (int off = 32; off; off >>= 1) {
        sum += __shfl_xor(sum, off);
        sq += __shfl_xor(sq, off);
    }
    float mu = sum * (1.f / 64.f);
    float var = sq * (1.f / 64.f) - mu * mu;
    float out = (x - mu) * rsqrtf(var + 1e-5f) * gn[col] + bn[col];
    h[node * D + col] = out;
}

// ---- e = LN(e + gelu([h[src]|h[dst]|e] @ Wem + bem)) via bf16 MFMA ----
// one wave per 16 edges; A-frags gathered direct from global (no LDS);
// B-frags from preconverted transposed bf16 Wt[32][160] (L1-resident).
__global__ void edge_update_mfma_kernel(const float* __restrict__ h, float* __restrict__ e,
                                        const int* __restrict__ src, const int* __restrict__ dst,
                                        const unsigned short* __restrict__ Wt,   // [32][160] bf16
                                        const float* __restrict__ bem,
                                        const float* __restrict__ ge,
                                        const float* __restrict__ be) {
    int wave = threadIdx.x >> 6;
    int lane = threadIdx.x & 63;
    int we = blockIdx.x * 64 + wave * 16;       // first edge of this wave
    int m = lane & 15;                          // A-row / C-col index
    int quad = lane >> 4;
    int edge_m = we + m;
    int s_idx = src[edge_m], d_idx = dst[edge_m];

    // A-operand source pointers for the 5 K-steps (8 consecutive floats each)
    const float* aptr0 = h + (size_t)s_idx * D + quad * 8;
    const float* aptr2 = h + (size_t)d_idx * D + quad * 8;
    const float* aptr4 = e + (size_t)edge_m * DE + quad * 8;
    const float* aptrs[5] = {aptr0, aptr0 + 32, aptr2, aptr2 + 32, aptr4};

    f32x4 c0 = {0.f, 0.f, 0.f, 0.f};
    f32x4 c1 = {0.f, 0.f, 0.f, 0.f};

#pragma unroll
    for (int ks = 0; ks < 5; ks++) {
        float4 x0 = *(const float4*)(aptrs[ks]);
        float4 x1 = *(const float4*)(aptrs[ks] + 4);
        bf16x8 a;
        a[0] = f2b(x0.x); a[1] = f2b(x0.y); a[2] = f2b(x0.z); a[3] = f2b(x0.w);
        a[4] = f2b(x1.x); a[5] = f2b(x1.y); a[6] = f2b(x1.z); a[7] = f2b(x1.w);
        // B[k = ks*32 + quad*8 + j][n]; Wt is [n][k] so j is contiguous
        const unsigned short* w0 = Wt + m * 160 + ks * 32 + quad * 8;
        bf16x8 b0 = *(const bf16x8*)(w0);
        bf16x8 b1 = *(const bf16x8*)(w0 + 16 * 160);
        c0 = __builtin_amdgcn_mfma_f32_16x16x32_bf16(a, b0, c0, 0, 0, 0);
        c1 = __builtin_amdgcn_mfma_f32_16x16x32_bf16(a, b1, c1, 0, 0, 0);
    }

    // epilogue: C/D layout col=lane&15, row=quad*4+reg
    float bm0 = bem[m], bm1 = bem[m + 16];
    float g0 = ge[m], g1 = ge[m + 16];
    float bb0 = be[m], bb1 = be[m + 16];
#pragma unroll
    for (int reg = 0; reg < 4; reg++) {
        int er = we + quad * 4 + reg;
        float y0 = c0[reg] + bm0;
        float y1 = c1[reg] + bm1;
        // gelu (tanh approx): 0.5*x*(1+tanh(0.79788456*(x+0.044715*x^3)))
        float u0 = 1.5957691216057308f * (y0 + 0.044715f * y0 * y0 * y0);  // 2*0.79788456*
        float u1 = 1.5957691216057308f * (y1 + 0.044715f * y1 * y1 * y1);
        float t0 = 1.f - 2.f / (1.f + __expf(u0));
        float t1 = 1.f - 2.f / (1.f + __expf(u1));
        y0 = 0.5f * y0 * (1.f + t0);
        y1 = 0.5f * y1 * (1.f + t1);
        float eo0 = e[(size_t)er * DE + m];
        float eo1 = e[(size_t)er * DE + m + 16];
        y0 += eo0;
        y1 += eo1;
        float s = y0 + y1, sq = y0 * y0 + y1 * y1;
#pragma unroll
        for (int off = 1; off < 16; off <<= 1) {
            s += __shfl_xor(s, off, 16);
            sq += __shfl_xor(sq, off, 16);
        }
        float mu = s * (1.f / 32.f);
        float var = sq * (1.f / 32.f) - mu * mu;
        float inv = rsqrtf(var + 1e-5f);
        e[(size_t)er * DE + m] = (y0 - mu) * inv * g0 + bb0;
        e[(size_t)er * DE + m + 16] = (y1 - mu) * inv * g1 + bb1;
    }
}

extern "C" void kernel_launch(void* const* d_in, const int* in_sizes, int n_in,
                              void* d_out, int out_size, void* d_ws, size_t ws_size,
                              hipStream_t stream) {
    const float* node_features = (const float*)d_in[0];
    float* e = (float*)d_in[1];     // updated in place; harness restores inputs
    const int* edge_index = (const int*)d_in[2];
    const int* src = edge_index;
    const int* dst = edge_index + NE;
    const float* Wq = (const float*)d_in[3];
    const float* Wk = (const float*)d_in[4];
    const float* Wv = (const float*)d_in[5];
    const float* Wo = (const float*)d_in[6];
    const float* We = (const float*)d_in[7];
    const float* Wem = (const float*)d_in[8];
    const float* bem = (const float*)d_in[9];
    const float* gn = (const float*)d_in[10];
    const float* bn = (const float*)d_in[11];
    const float* ge = (const float*)d_in[12];
    const float* be = (const float*)d_in[13];

    float* h = (float*)d_out;       // h lives in d_out

    float* ws = (float*)d_ws;
    float* q = ws;                                   // N*D
    float* k = q + NN * D;                           // N*D
    float* v = k + NN * D;                           // N*D
    float* agg = v + NN * D;                         // N*D
    float* ebias = agg + NN * D;                     // E*H
    int* offsets = (int*)(ebias + (size_t)NE * H);   // NN
    int* cursor = offsets + NN;                      // NN
    int* bsum = cursor + NN;                         // 64
    int* sorted_eid = bsum + 64;                     // NE
    unsigned short* Wt = (unsigned short*)(sorted_eid + NE);  // L*32*160 bf16

    const int NB = (NN + 1023) / 1024;

    // ---- CSR build + weight preconvert (inputs constant; rebuilt every launch) ----
    hipMemsetAsync(cursor, 0, NN * sizeof(int), stream);
    deg_kernel<<<(NE + 255) / 256, 256, 0, stream>>>(dst, cursor);
    block_sum_kernel<<<NB, 256, 0, stream>>>(cursor, bsum);
    scan_bsum_kernel<<<1, 64, 0, stream>>>(bsum, NB);
    scan_block_kernel<<<NB, 256, 0, stream>>>(cursor, bsum, offsets);
    hipMemsetAsync(cursor, 0, NN * sizeof(int), stream);
    scatter_kernel<<<(NE + 255) / 256, 256, 0, stream>>>(dst, offsets, cursor, sorted_eid);
    wconv_kernel<<<(L * 32 * 160 + 255) / 256, 256, 0, stream>>>(Wem, Wt);

    hipMemcpyAsync(h, node_features, (size_t)NN * D * sizeof(float),
                   hipMemcpyDeviceToDevice, stream);

    for (int layer = 0; layer < L; layer++) {
        const float* Wq_l = Wq + layer * D * D;
        const float* Wk_l = Wk + layer * D * D;
        const float* Wv_l = Wv + layer * D * D;
        const float* Wo_l = Wo + layer * D * D;
        const float* We_l = We + layer * DE * H;
        const unsigned short* Wt_l = Wt + layer * 32 * 160;
        const float* bem_l = bem + layer * DE;
        const float* gn_l = gn + layer * D;
        const float* bn_l = bn + layer * D;
        const float* ge_l = ge + layer * DE;
        const float* be_l = be + layer * DE;

        qkv_kernel<<<(NN + 3) / 4, dim3(64, 4), 0, stream>>>(h, Wq_l, Wk_l, Wv_l, q, k, v);
        ebias_kernel<<<(NE * H + 255) / 256, 256, 0, stream>>>(e, We_l, ebias);
        attn_kernel<<<(NN + 3) / 4, dim3(64, 4), 0, stream>>>(q, k, v, ebias, src,
                                                              offsets, sorted_eid, agg);
        node_update_kernel<<<(NN + 3) / 4, dim3(64, 4), 0, stream>>>(h, agg, Wo_l, gn_l, bn_l);
        edge_update_mfma_kernel<<<NE / 64, 256, 0, stream>>>(h, e, src, dst, Wt_l,
                                                             bem_l, ge_l, be_l);
    }
}

// Round 4
// 1919.414 us; speedup vs baseline: 4.3041x; 1.2420x over previous
//
#include <hip/hip_runtime.h>
#include <hip/hip_bf16.h>
#include <math.h>

#define NN 50000
#define NE 1600000
#define D 64
#define DE 32
#define H 4
#define DH 16
#define L 3

typedef __attribute__((ext_vector_type(8))) short bf16x8;
typedef __attribute__((ext_vector_type(4))) float f32x4;

__device__ __forceinline__ short f2b(float f) {
    __hip_bfloat16 h = __float2bfloat16(f);
    short s;
    __builtin_memcpy(&s, &h, 2);
    return s;
}
__device__ __forceinline__ float b2f_lo(unsigned int p) {
    unsigned int x = p << 16;
    float f; __builtin_memcpy(&f, &x, 4); return f;
}
__device__ __forceinline__ float b2f_hi(unsigned int p) {
    unsigned int x = p & 0xffff0000u;
    float f; __builtin_memcpy(&f, &x, 4); return f;
}

// ======================= CSR build (per launch) =======================

__global__ void deg_kernel(const int* __restrict__ dst, int* __restrict__ cnt) {
    int e = blockIdx.x * 256 + threadIdx.x;
    if (e >= NE) return;
    atomicAdd(&cnt[dst[e]], 1);
}

__global__ void block_sum_kernel(const int* __restrict__ cnt, int* __restrict__ bsum) {
    int b = blockIdx.x, t = threadIdx.x;
    int base = b * 1024 + t * 4;
    int s = 0;
#pragma unroll
    for (int i = 0; i < 4; i++) { int idx = base + i; if (idx < NN) s += cnt[idx]; }
#pragma unroll
    for (int off = 32; off; off >>= 1) s += __shfl_down(s, off);
    __shared__ int wsum[4];
    if ((t & 63) == 0) wsum[t >> 6] = s;
    __syncthreads();
    if (t == 0) bsum[b] = wsum[0] + wsum[1] + wsum[2] + wsum[3];
}

__global__ void scan_bsum_kernel(int* __restrict__ bsum, int nb) {
    if (blockIdx.x == 0 && threadIdx.x == 0) {
        int run = 0;
        for (int i = 0; i < nb; i++) { int c = bsum[i]; bsum[i] = run; run += c; }
    }
}

__global__ void scan_block_kernel(const int* __restrict__ cnt, const int* __restrict__ bsum,
                                  int* __restrict__ offsets) {
    int b = blockIdx.x, t = threadIdx.x;
    int base = b * 1024 + t * 4;
    int v[4]; int s = 0;
#pragma unroll
    for (int i = 0; i < 4; i++) { int idx = base + i; v[i] = (idx < NN) ? cnt[idx] : 0; s += v[i]; }
    int lane = t & 63, w = t >> 6;
    int x = s;
#pragma unroll
    for (int off = 1; off < 64; off <<= 1) {
        int y = __shfl_up(x, off);
        if (lane >= off) x += y;
    }
    __shared__ int wsum[4];
    if (lane == 63) wsum[w] = x;
    __syncthreads();
    int woff = 0;
    for (int i = 0; i < w; i++) woff += wsum[i];
    int run = bsum[b] + woff + x - s;
#pragma unroll
    for (int i = 0; i < 4; i++) {
        int idx = base + i;
        if (idx < NN) offsets[idx] = run;
        run += v[i];
    }
}

// emit sorted_src (srcs in dst-sorted order) and rank (edge -> sorted position)
__global__ void scatter_kernel(const int* __restrict__ src, const int* __restrict__ dst,
                               const int* __restrict__ offsets,
                               int* __restrict__ cursor,
                               int* __restrict__ sorted_src, int* __restrict__ rank) {
    int e = blockIdx.x * 256 + threadIdx.x;
    if (e >= NE) return;
    int d0 = dst[e];
    int pos = atomicAdd(&cursor[d0], 1);
    int position = offsets[d0] + pos;
    sorted_src[position] = src[e];
    rank[e] = position;
}

// ---- Wem[L][160][32] fp32 -> Wt[L][32][160] bf16 (transposed, once per launch) ----
__global__ void wconv_kernel(const float* __restrict__ Wem, unsigned short* __restrict__ Wt) {
    int t = blockIdx.x * 256 + threadIdx.x;
    if (t >= L * 32 * 160) return;
    int l = t / 5120;
    int r = t % 5120;
    int n = r / 160;
    int k = r % 160;
    Wt[t] = (unsigned short)f2b(Wem[l * 5120 + k * 32 + n]);
}

// ---- h = node_features (fp32) + hb = bf16(node_features) ----
__global__ void hconv_kernel(const float* __restrict__ nf, float* __restrict__ h,
                             unsigned short* __restrict__ hb) {
    int t = blockIdx.x * 256 + threadIdx.x;
    if (t >= NN * D) return;
    float x = nf[t];
    h[t] = x;
    hb[t] = (unsigned short)f2b(x);
}

// ======================= per-layer kernels =======================

// ---- q = (h@Wq)*0.25 ; kv[node][col] = pack(bf16(k), bf16(v)) ----
__global__ void qkv_kernel(const float* __restrict__ h,
                           const float* __restrict__ Wq,
                           const float* __restrict__ Wk,
                           const float* __restrict__ Wv,
                           float* __restrict__ q, unsigned int* __restrict__ kv) {
    __shared__ float sWq[D * D], sWk[D * D], sWv[D * D];
    __shared__ float sh[4][D];
    int col = threadIdx.x;
    int r = threadIdx.y;
    int tid = r * 64 + col;
    for (int i = tid; i < D * D; i += 256) {
        sWq[i] = Wq[i]; sWk[i] = Wk[i]; sWv[i] = Wv[i];
    }
    int node = blockIdx.x * 4 + r;
    if (node < NN) sh[r][col] = h[node * D + col];
    __syncthreads();
    if (node >= NN) return;
    float aq = 0.f, ak = 0.f, av = 0.f;
#pragma unroll
    for (int kk = 0; kk < D; kk++) {
        float hv = sh[r][kk];
        aq += hv * sWq[kk * D + col];
        ak += hv * sWk[kk * D + col];
        av += hv * sWv[kk * D + col];
    }
    q[node * D + col] = aq * 0.25f;   // fold 1/sqrt(16)
    unsigned int kb = (unsigned int)(unsigned short)f2b(ak);
    unsigned int vb = (unsigned int)(unsigned short)f2b(av);
    kv[node * D + col] = (vb << 16) | kb;
}

// ---- ebias_s[rank[e], h] = e_row . We[:,h]  (written in dst-sorted order) ----
__global__ void ebias_kernel(const float* __restrict__ e, const float* __restrict__ We,
                             const int* __restrict__ rank, float* __restrict__ ebias_s) {
    int t = blockIdx.x * 256 + threadIdx.x;
    if (t >= NE * H) return;
    int edge = t >> 2;
    int hh = t & 3;
    const float* ep = e + (size_t)edge * DE;
    float bias = 0.f;
#pragma unroll
    for (int i = 0; i < DE; i++) bias += ep[i] * We[i * H + hh];
    ebias_s[rank[edge] * H + hh] = bias;
}

// ---- fused per-dst-node online-softmax attention + aggregation ----
__global__ void attn_kernel(const float* __restrict__ q, const unsigned int* __restrict__ kv,
                            const float* __restrict__ ebias_s,
                            const int* __restrict__ sorted_src,
                            const int* __restrict__ offsets,
                            float* __restrict__ agg) {
    int node = blockIdx.x * 4 + threadIdx.y;
    node = __builtin_amdgcn_readfirstlane(node);   // wave-uniform -> scalar loads
    if (node >= NN) return;
    int lane = threadIdx.x;
    int hh = lane >> 4;
    float qv = q[node * D + lane];
    int beg = offsets[node];
    int end = (node == NN - 1) ? NE : offsets[node + 1];
    float result = 0.f;
    if (beg < end) {
        float mmax = -INFINITY, den = 0.f, acc = 0.f;
        int last = end - 1;
        int s1 = sorted_src[beg];
        unsigned int kv1 = kv[s1 * D + lane];
        float b1 = ebias_s[beg * H + hh];
        int s2 = sorted_src[(beg + 1 < end) ? beg + 1 : last];
        for (int i = beg; i < end; i++) {
            // issue next-iteration loads first (1-deep pipeline)
            int inext = (i + 1 < end) ? i + 1 : last;
            unsigned int kv2 = kv[s2 * D + lane];
            float b2 = ebias_s[inext * H + hh];
            int s3 = sorted_src[(i + 2 < end) ? i + 2 : last];
            // compute edge i
            float kf = b2f_lo(kv1);
            float vf = b2f_hi(kv1);
            float dot = qv * kf;
#pragma unroll
            for (int off = 1; off < 16; off <<= 1) dot += __shfl_xor(dot, off, 16);
            float score = dot + b1;
            float nm = fmaxf(mmax, score);
            float scale = __expf(mmax - nm);
            float p = __expf(score - nm);
            den = den * scale + p;
            acc = acc * scale + p * vf;
            mmax = nm;
            kv1 = kv2; b1 = b2; s2 = s3;
        }
        result = acc / (den + 1e-9f);
    }
    agg[node * D + lane] = result;
}

// ---- h = LN(h + agg @ Wo) ; also writes bf16 shadow hb ----
__global__ void node_update_kernel(float* __restrict__ h, const float* __restrict__ agg,
                                   const float* __restrict__ Wo,
                                   const float* __restrict__ gn,
                                   const float* __restrict__ bn,
                                   unsigned short* __restrict__ hb) {
    __shared__ float sWo[D * D];
    __shared__ float sagg[4][D];
    int col = threadIdx.x, r = threadIdx.y;
    int tid = r * 64 + col;
    for (int i = tid; i < D * D; i += 256) sWo[i] = Wo[i];
    int node = blockIdx.x * 4 + r;
    if (node < NN) sagg[r][col] = agg[node * D + col];
    __syncthreads();
    if (node >= NN) return;
    float acc = 0.f;
#pragma unroll
    for (int kk = 0; kk < D; kk++) acc += sagg[r][kk] * sWo[kk * D + col];
    float x = h[node * D + col] + acc;
    float sum = x, sq = x * x;
#pragma unroll
    for (int off = 32; off; off >>= 1) {
        sum += __shfl_xor(sum, off);
        sq += __shfl_xor(sq, off);
    }
    float mu = sum * (1.f / 64.f);
    float var = sq * (1.f / 64.f) - mu * mu;
    float out = (x - mu) * rsqrtf(var + 1e-5f) * gn[col] + bn[col];
    h[node * D + col] = out;
    hb[node * D + col] = (unsigned short)f2b(out);
}

// ---- e = LN(e + gelu([h[src]|h[dst]|e] @ Wem + bem)) via bf16 MFMA ----
// A-frags: h gathers from bf16 shadow hb (16 B/lane), e from fp32 + convert.
__global__ void edge_update_mfma_kernel(const unsigned short* __restrict__ hb,
                                        float* __restrict__ e,
                                        const int* __restrict__ src, const int* __restrict__ dst,
                                        const unsigned short* __restrict__ Wt,   // [32][160] bf16
                                        const float* __restrict__ bem,
                                        const float* __restrict__ ge,
                                        const float* __restrict__ be) {
    int wave = threadIdx.x >> 6;
    int lane = threadIdx.x & 63;
    int we = blockIdx.x * 64 + wave * 16;       // first edge of this wave
    int m = lane & 15;
    int quad = lane >> 4;
    int edge_m = we + m;
    int s_idx = src[edge_m], d_idx = dst[edge_m];

    const unsigned short* as = hb + (size_t)s_idx * D + quad * 8;
    const unsigned short* ad = hb + (size_t)d_idx * D + quad * 8;
    const float* ae = e + (size_t)edge_m * DE + quad * 8;
    const unsigned short* w0 = Wt + m * 160 + quad * 8;

    f32x4 c0 = {0.f, 0.f, 0.f, 0.f};
    f32x4 c1 = {0.f, 0.f, 0.f, 0.f};

#pragma unroll
    for (int ks = 0; ks < 4; ks++) {
        const unsigned short* ap = (ks < 2) ? as : ad;
        bf16x8 a = *(const bf16x8*)(ap + (ks & 1) * 32);
        bf16x8 b0 = *(const bf16x8*)(w0 + ks * 32);
        bf16x8 b1 = *(const bf16x8*)(w0 + ks * 32 + 16 * 160);
        c0 = __builtin_amdgcn_mfma_f32_16x16x32_bf16(a, b0, c0, 0, 0, 0);
        c1 = __builtin_amdgcn_mfma_f32_16x16x32_bf16(a, b1, c1, 0, 0, 0);
    }
    {
        float4 x0 = *(const float4*)(ae);
        float4 x1 = *(const float4*)(ae + 4);
        bf16x8 a;
        a[0] = f2b(x0.x); a[1] = f2b(x0.y); a[2] = f2b(x0.z); a[3] = f2b(x0.w);
        a[4] = f2b(x1.x); a[5] = f2b(x1.y); a[6] = f2b(x1.z); a[7] = f2b(x1.w);
        bf16x8 b0 = *(const bf16x8*)(w0 + 4 * 32);
        bf16x8 b1 = *(const bf16x8*)(w0 + 4 * 32 + 16 * 160);
        c0 = __builtin_amdgcn_mfma_f32_16x16x32_bf16(a, b0, c0, 0, 0, 0);
        c1 = __builtin_amdgcn_mfma_f32_16x16x32_bf16(a, b1, c1, 0, 0, 0);
    }

    // epilogue: C/D layout col=lane&15, row=quad*4+reg
    float bm0 = bem[m], bm1 = bem[m + 16];
    float g0 = ge[m], g1 = ge[m + 16];
    float bb0 = be[m], bb1 = be[m + 16];
#pragma unroll
    for (int reg = 0; reg < 4; reg++) {
        int er = we + quad * 4 + reg;
        float y0 = c0[reg] + bm0;
        float y1 = c1[reg] + bm1;
        float u0 = 1.5957691216057308f * (y0 + 0.044715f * y0 * y0 * y0);
        float u1 = 1.5957691216057308f * (y1 + 0.044715f * y1 * y1 * y1);
        float t0 = 1.f - 2.f / (1.f + __expf(u0));
        float t1 = 1.f - 2.f / (1.f + __expf(u1));
        y0 = 0.5f * y0 * (1.f + t0);
        y1 = 0.5f * y1 * (1.f + t1);
        float eo0 = e[(size_t)er * DE + m];
        float eo1 = e[(size_t)er * DE + m + 16];
        y0 += eo0;
        y1 += eo1;
        float s = y0 + y1, sq = y0 * y0 + y1 * y1;
#pragma unroll
        for (int off = 1; off < 16; off <<= 1) {
            s += __shfl_xor(s, off, 16);
            sq += __shfl_xor(sq, off, 16);
        }
        float mu = s * (1.f / 32.f);
        float var = sq * (1.f / 32.f) - mu * mu;
        float inv = rsqrtf(var + 1e-5f);
        e[(size_t)er * DE + m] = (y0 - mu) * inv * g0 + bb0;
        e[(size_t)er * DE + m + 16] = (y1 - mu) * inv * g1 + bb1;
    }
}

extern "C" void kernel_launch(void* const* d_in, const int* in_sizes, int n_in,
                              void* d_out, int out_size, void* d_ws, size_t ws_size,
                              hipStream_t stream) {
    const float* node_features = (const float*)d_in[0];
    float* e = (float*)d_in[1];     // updated in place; harness restores inputs
    const int* edge_index = (const int*)d_in[2];
    const int* src = edge_index;
    const int* dst = edge_index + NE;
    const float* Wq = (const float*)d_in[3];
    const float* Wk = (const float*)d_in[4];
    const float* Wv = (const float*)d_in[5];
    const float* Wo = (const float*)d_in[6];
    const float* We = (const float*)d_in[7];
    const float* Wem = (const float*)d_in[8];
    const float* bem = (const float*)d_in[9];
    const float* gn = (const float*)d_in[10];
    const float* bn = (const float*)d_in[11];
    const float* ge = (const float*)d_in[12];
    const float* be = (const float*)d_in[13];

    float* h = (float*)d_out;       // h lives in d_out

    float* ws = (float*)d_ws;
    float* q = ws;                                       // N*D f32
    unsigned int* kv = (unsigned int*)(q + NN * D);      // N*D u32 (packed bf16 k|v)
    float* agg = (float*)(kv + NN * D);                  // N*D f32
    float* ebias_s = agg + NN * D;                       // E*H f32 (sorted order)
    int* offsets = (int*)(ebias_s + (size_t)NE * H);     // NN
    int* cursor = offsets + NN;                          // NN
    int* bsum = cursor + NN;                             // 64
    int* sorted_src = bsum + 64;                         // NE (+pad)
    int* rank = sorted_src + NE + 64;                    // NE
    unsigned short* Wt = (unsigned short*)(rank + NE);   // L*32*160 bf16
    unsigned short* hb = Wt + L * 32 * 160;              // N*D bf16

    const int NB = (NN + 1023) / 1024;

    // ---- CSR build + weight preconvert (inputs constant; rebuilt every launch) ----
    hipMemsetAsync(cursor, 0, NN * sizeof(int), stream);
    deg_kernel<<<(NE + 255) / 256, 256, 0, stream>>>(dst, cursor);
    block_sum_kernel<<<NB, 256, 0, stream>>>(cursor, bsum);
    scan_bsum_kernel<<<1, 64, 0, stream>>>(bsum, NB);
    scan_block_kernel<<<NB, 256, 0, stream>>>(cursor, bsum, offsets);
    hipMemsetAsync(cursor, 0, NN * sizeof(int), stream);
    scatter_kernel<<<(NE + 255) / 256, 256, 0, stream>>>(src, dst, offsets, cursor,
                                                         sorted_src, rank);
    wconv_kernel<<<(L * 32 * 160 + 255) / 256, 256, 0, stream>>>(Wem, Wt);
    hconv_kernel<<<(NN * D + 255) / 256, 256, 0, stream>>>(node_features, h, hb);

    for (int layer = 0; layer < L; layer++) {
        const float* Wq_l = Wq + layer * D * D;
        const float* Wk_l = Wk + layer * D * D;
        const float* Wv_l = Wv + layer * D * D;
        const float* Wo_l = Wo + layer * D * D;
        const float* We_l = We + layer * DE * H;
        const unsigned short* Wt_l = Wt + layer * 32 * 160;
        const float* bem_l = bem + layer * DE;
        const float* gn_l = gn + layer * D;
        const float* bn_l = bn + layer * D;
        const float* ge_l = ge + layer * DE;
        const float* be_l = be + layer * DE;

        qkv_kernel<<<(NN + 3) / 4, dim3(64, 4), 0, stream>>>(h, Wq_l, Wk_l, Wv_l, q, kv);
        ebias_kernel<<<(NE * H + 255) / 256, 256, 0, stream>>>(e, We_l, rank, ebias_s);
        attn_kernel<<<(NN + 3) / 4, dim3(64, 4), 0, stream>>>(q, kv, ebias_s, sorted_src,
                                                              offsets, agg);
        node_update_kernel<<<(NN + 3) / 4, dim3(64, 4), 0, stream>>>(h, agg, Wo_l,
                                                                     gn_l, bn_l, hb);
        edge_update_mfma_kernel<<<NE / 64, 256, 0, stream>>>(hb, e, src, dst, Wt_l,
                                                             bem_l, ge_l, be_l);
    }
}

// Round 5
// 1651.764 us; speedup vs baseline: 5.0015x; 1.1620x over previous
//
#include <hip/hip_runtime.h>
#include <hip/hip_bf16.h>
#include <math.h>

#define NN 50000
#define NE 1600000
#define D 64
#define DE 32
#define H 4
#define DH 16
#define L 3

typedef __attribute__((ext_vector_type(8))) short bf16x8;
typedef __attribute__((ext_vector_type(4))) float f32x4;

__device__ __forceinline__ short f2b(float f) {
    __hip_bfloat16 h = __float2bfloat16(f);
    short s;
    __builtin_memcpy(&s, &h, 2);
    return s;
}
__device__ __forceinline__ float b2f_lo(unsigned int p) {
    unsigned int x = p << 16;
    float f; __builtin_memcpy(&f, &x, 4); return f;
}
__device__ __forceinline__ float b2f_hi(unsigned int p) {
    unsigned int x = p & 0xffff0000u;
    float f; __builtin_memcpy(&f, &x, 4); return f;
}

// ======================= CSR build (per launch) =======================

__global__ void deg_kernel(const int* __restrict__ dst, int* __restrict__ cnt) {
    int e = blockIdx.x * 256 + threadIdx.x;
    if (e >= NE) return;
    atomicAdd(&cnt[dst[e]], 1);
}

__global__ void block_sum_kernel(const int* __restrict__ cnt, int* __restrict__ bsum) {
    int b = blockIdx.x, t = threadIdx.x;
    int base = b * 1024 + t * 4;
    int s = 0;
#pragma unroll
    for (int i = 0; i < 4; i++) { int idx = base + i; if (idx < NN) s += cnt[idx]; }
#pragma unroll
    for (int off = 32; off; off >>= 1) s += __shfl_down(s, off);
    __shared__ int wsum[4];
    if ((t & 63) == 0) wsum[t >> 6] = s;
    __syncthreads();
    if (t == 0) bsum[b] = wsum[0] + wsum[1] + wsum[2] + wsum[3];
}

__global__ void scan_bsum_kernel(int* __restrict__ bsum, int nb) {
    if (blockIdx.x == 0 && threadIdx.x == 0) {
        int run = 0;
        for (int i = 0; i < nb; i++) { int c = bsum[i]; bsum[i] = run; run += c; }
    }
}

__global__ void scan_block_kernel(const int* __restrict__ cnt, const int* __restrict__ bsum,
                                  int* __restrict__ offsets) {
    int b = blockIdx.x, t = threadIdx.x;
    int base = b * 1024 + t * 4;
    int v[4]; int s = 0;
#pragma unroll
    for (int i = 0; i < 4; i++) { int idx = base + i; v[i] = (idx < NN) ? cnt[idx] : 0; s += v[i]; }
    int lane = t & 63, w = t >> 6;
    int x = s;
#pragma unroll
    for (int off = 1; off < 64; off <<= 1) {
        int y = __shfl_up(x, off);
        if (lane >= off) x += y;
    }
    __shared__ int wsum[4];
    if (lane == 63) wsum[w] = x;
    __syncthreads();
    int woff = 0;
    for (int i = 0; i < w; i++) woff += wsum[i];
    int run = bsum[b] + woff + x - s;
#pragma unroll
    for (int i = 0; i < 4; i++) {
        int idx = base + i;
        if (idx < NN) offsets[idx] = run;
        run += v[i];
    }
}

__global__ void scatter_kernel(const int* __restrict__ src, const int* __restrict__ dst,
                               const int* __restrict__ offsets,
                               int* __restrict__ cursor,
                               int* __restrict__ sorted_src, int* __restrict__ rank) {
    int e = blockIdx.x * 256 + threadIdx.x;
    if (e >= NE) return;
    int d0 = dst[e];
    int pos = atomicAdd(&cursor[d0], 1);
    int position = offsets[d0] + pos;
    sorted_src[position] = src[e];
    rank[e] = position;
}

// ---- Wem[L][160][32] fp32 -> Wt[L][32][160] bf16 (transposed) ----
__global__ void wconv_kernel(const float* __restrict__ Wem, unsigned short* __restrict__ Wt) {
    int t = blockIdx.x * 256 + threadIdx.x;
    if (t >= L * 32 * 160) return;
    int l = t / 5120;
    int r = t % 5120;
    int n = r / 160;
    int k = r % 160;
    Wt[t] = (unsigned short)f2b(Wem[l * 5120 + k * 32 + n]);
}

// ---- h = node_features (fp32) + hb = bf16(node_features) ----
__global__ void hconv_kernel(const float* __restrict__ nf, float* __restrict__ h,
                             unsigned short* __restrict__ hb) {
    int t = blockIdx.x * 256 + threadIdx.x;
    if (t >= NN * D) return;
    float x = nf[t];
    h[t] = x;
    hb[t] = (unsigned short)f2b(x);
}

// ======================= per-layer kernels =======================

// ---- q = (h@Wq)*0.25 ; kv = pack(bf16(k), bf16(v)) ; 16 nodes/block ----
__global__ void qkv_kernel(const float* __restrict__ h,
                           const float* __restrict__ Wq,
                           const float* __restrict__ Wk,
                           const float* __restrict__ Wv,
                           float* __restrict__ q, unsigned int* __restrict__ kv) {
    __shared__ float sW[3 * 4096];   // 48 KB
    __shared__ float sh[16][D];
    int col = threadIdx.x;           // 0..63
    int wv = threadIdx.y;            // 0..3
    int tid = wv * 64 + col;
    int base = blockIdx.x * 16;
    for (int i = tid; i < 4096; i += 256) {
        sW[i] = Wq[i]; sW[4096 + i] = Wk[i]; sW[8192 + i] = Wv[i];
    }
    for (int i = tid; i < 16 * D; i += 256) {
        int n = base + (i >> 6);
        sh[i >> 6][i & 63] = h[n * D + (i & 63)];   // NN%16==0, always in range
    }
    __syncthreads();
#pragma unroll
    for (int it = 0; it < 4; it++) {
        int ln = wv * 4 + it;
        int node = base + ln;
        float aq = 0.f, ak = 0.f, av = 0.f;
#pragma unroll
        for (int kk = 0; kk < D; kk++) {
            float hv = sh[ln][kk];
            aq += hv * sW[kk * D + col];
            ak += hv * sW[4096 + kk * D + col];
            av += hv * sW[8192 + kk * D + col];
        }
        q[node * D + col] = aq * 0.25f;
        unsigned int kb = (unsigned int)(unsigned short)f2b(ak);
        unsigned int vb = (unsigned int)(unsigned short)f2b(av);
        kv[node * D + col] = (vb << 16) | kb;
    }
}

// ---- standalone ebias (layer 0 only): ebias_s[rank[e],h] = e_row . We[:,h] ----
__global__ void ebias_kernel(const float* __restrict__ e, const float* __restrict__ We,
                             const int* __restrict__ rank, float* __restrict__ ebias_s) {
    int t = blockIdx.x * 256 + threadIdx.x;
    if (t >= NE * H) return;
    int edge = t >> 2;
    int hh = t & 3;
    const float* ep = e + (size_t)edge * DE;
    float bias = 0.f;
#pragma unroll
    for (int i = 0; i < DE; i++) bias += ep[i] * We[i * H + hh];
    ebias_s[rank[edge] * H + hh] = bias;
}

// ---- fused per-dst-node online-softmax attention + aggregation (4-wide) ----
__global__ void attn_kernel(const float* __restrict__ q, const unsigned int* __restrict__ kv,
                            const float* __restrict__ ebias_s,
                            const int* __restrict__ sorted_src,
                            const int* __restrict__ offsets,
                            float* __restrict__ agg) {
    int node = blockIdx.x * 4 + threadIdx.y;
    node = __builtin_amdgcn_readfirstlane(node);
    if (node >= NN) return;
    int lane = threadIdx.x;
    int hh = lane >> 4;
    float qv = q[node * D + lane];
    int beg = offsets[node];
    int end = (node == NN - 1) ? NE : offsets[node + 1];
    float mmax = -INFINITY, den = 0.f, acc = 0.f;
    int i = beg;
    for (; i + 4 <= end; i += 4) {
        int s0 = sorted_src[i], s1 = sorted_src[i + 1];
        int s2 = sorted_src[i + 2], s3 = sorted_src[i + 3];
        unsigned int k0 = kv[s0 * D + lane];
        unsigned int k1 = kv[s1 * D + lane];
        unsigned int k2 = kv[s2 * D + lane];
        unsigned int k3 = kv[s3 * D + lane];
        float b0 = ebias_s[i * H + hh];
        float b1 = ebias_s[(i + 1) * H + hh];
        float b2 = ebias_s[(i + 2) * H + hh];
        float b3 = ebias_s[(i + 3) * H + hh];
        float d0 = qv * b2f_lo(k0), d1 = qv * b2f_lo(k1);
        float d2 = qv * b2f_lo(k2), d3 = qv * b2f_lo(k3);
#pragma unroll
        for (int off = 1; off < 16; off <<= 1) {
            d0 += __shfl_xor(d0, off, 16);
            d1 += __shfl_xor(d1, off, 16);
            d2 += __shfl_xor(d2, off, 16);
            d3 += __shfl_xor(d3, off, 16);
        }
        d0 += b0; d1 += b1; d2 += b2; d3 += b3;
        float nm = fmaxf(mmax, fmaxf(fmaxf(d0, d1), fmaxf(d2, d3)));
        float p0 = __expf(d0 - nm), p1 = __expf(d1 - nm);
        float p2 = __expf(d2 - nm), p3 = __expf(d3 - nm);
        float scale = __expf(mmax - nm);
        den = den * scale + ((p0 + p1) + (p2 + p3));
        acc = acc * scale + (p0 * b2f_hi(k0) + p1 * b2f_hi(k1))
                          + (p2 * b2f_hi(k2) + p3 * b2f_hi(k3));
        mmax = nm;
    }
    for (; i < end; i++) {
        int s = sorted_src[i];
        unsigned int kvv = kv[s * D + lane];
        float b = ebias_s[i * H + hh];
        float dot = qv * b2f_lo(kvv);
#pragma unroll
        for (int off = 1; off < 16; off <<= 1) dot += __shfl_xor(dot, off, 16);
        float score = dot + b;
        float nm = fmaxf(mmax, score);
        float scale = __expf(mmax - nm);
        float p = __expf(score - nm);
        den = den * scale + p;
        acc = acc * scale + p * b2f_hi(kvv);
        mmax = nm;
    }
    agg[node * D + lane] = acc / (den + 1e-9f);
}

// ---- h = LN(h + agg @ Wo) + bf16 shadow ; 16 nodes/block ----
__global__ void node_update_kernel(float* __restrict__ h, const float* __restrict__ agg,
                                   const float* __restrict__ Wo,
                                   const float* __restrict__ gn,
                                   const float* __restrict__ bn,
                                   unsigned short* __restrict__ hb) {
    __shared__ float sWo[4096];      // 16 KB
    __shared__ float sagg[16][D];
    int col = threadIdx.x, wv = threadIdx.y;
    int tid = wv * 64 + col;
    int base = blockIdx.x * 16;
    for (int i = tid; i < 4096; i += 256) sWo[i] = Wo[i];
    for (int i = tid; i < 16 * D; i += 256) {
        int n = base + (i >> 6);
        sagg[i >> 6][i & 63] = agg[n * D + (i & 63)];
    }
    __syncthreads();
    float gcol = gn[col], bcol = bn[col];
#pragma unroll
    for (int it = 0; it < 4; it++) {
        int ln = wv * 4 + it;
        int node = base + ln;
        float acc = 0.f;
#pragma unroll
        for (int kk = 0; kk < D; kk++) acc += sagg[ln][kk] * sWo[kk * D + col];
        float x = h[node * D + col] + acc;
        float sum = x, sq = x * x;
#pragma unroll
        for (int off = 32; off; off >>= 1) {
            sum += __shfl_xor(sum, off);
            sq += __shfl_xor(sq, off);
        }
        float mu = sum * (1.f / 64.f);
        float var = sq * (1.f / 64.f) - mu * mu;
        float out = (x - mu) * rsqrtf(var + 1e-5f) * gcol + bcol;
        h[node * D + col] = out;
        hb[node * D + col] = (unsigned short)f2b(out);
    }
}

// ---- e = LN(e + gelu([h[src]|h[dst]|e] @ Wem + bem)) via bf16 MFMA,
//      with next-layer ebias fused into the epilogue ----
__global__ void edge_update_mfma_kernel(const unsigned short* __restrict__ hb,
                                        float* __restrict__ e,
                                        const int* __restrict__ src, const int* __restrict__ dst,
                                        const unsigned short* __restrict__ Wt,   // [32][160] bf16
                                        const float* __restrict__ bem,
                                        const float* __restrict__ ge,
                                        const float* __restrict__ be,
                                        const float* __restrict__ We_next,       // [32][4]
                                        const int* __restrict__ rank,
                                        float* __restrict__ ebias_s,
                                        int do_bias) {
    int wave = threadIdx.x >> 6;
    int lane = threadIdx.x & 63;
    int we = blockIdx.x * 64 + wave * 16;
    int m = lane & 15;
    int quad = lane >> 4;
    int edge_m = we + m;
    int s_idx = src[edge_m], d_idx = dst[edge_m];

    const unsigned short* as = hb + (size_t)s_idx * D + quad * 8;
    const unsigned short* ad = hb + (size_t)d_idx * D + quad * 8;
    const float* ae = e + (size_t)edge_m * DE + quad * 8;
    const unsigned short* w0 = Wt + m * 160 + quad * 8;

    f32x4 c0 = {0.f, 0.f, 0.f, 0.f};
    f32x4 c1 = {0.f, 0.f, 0.f, 0.f};

#pragma unroll
    for (int ks = 0; ks < 4; ks++) {
        const unsigned short* ap = (ks < 2) ? as : ad;
        bf16x8 a = *(const bf16x8*)(ap + (ks & 1) * 32);
        bf16x8 b0 = *(const bf16x8*)(w0 + ks * 32);
        bf16x8 b1 = *(const bf16x8*)(w0 + ks * 32 + 16 * 160);
        c0 = __builtin_amdgcn_mfma_f32_16x16x32_bf16(a, b0, c0, 0, 0, 0);
        c1 = __builtin_amdgcn_mfma_f32_16x16x32_bf16(a, b1, c1, 0, 0, 0);
    }
    {
        float4 x0 = *(const float4*)(ae);
        float4 x1 = *(const float4*)(ae + 4);
        bf16x8 a;
        a[0] = f2b(x0.x); a[1] = f2b(x0.y); a[2] = f2b(x0.z); a[3] = f2b(x0.w);
        a[4] = f2b(x1.x); a[5] = f2b(x1.y); a[6] = f2b(x1.z); a[7] = f2b(x1.w);
        bf16x8 b0 = *(const bf16x8*)(w0 + 4 * 32);
        bf16x8 b1 = *(const bf16x8*)(w0 + 4 * 32 + 16 * 160);
        c0 = __builtin_amdgcn_mfma_f32_16x16x32_bf16(a, b0, c0, 0, 0, 0);
        c1 = __builtin_amdgcn_mfma_f32_16x16x32_bf16(a, b1, c1, 0, 0, 0);
    }

    // epilogue: C/D layout col=lane&15, row=quad*4+reg
    float bm0 = bem[m], bm1 = bem[m + 16];
    float g0 = ge[m], g1 = ge[m + 16];
    float bb0 = be[m], bb1 = be[m + 16];
    float4 wn0 = {0, 0, 0, 0}, wn1 = {0, 0, 0, 0};
    if (do_bias) {
        wn0 = *(const float4*)(We_next + m * 4);
        wn1 = *(const float4*)(We_next + (m + 16) * 4);
    }
#pragma unroll
    for (int reg = 0; reg < 4; reg++) {
        int er = we + quad * 4 + reg;
        float y0 = c0[reg] + bm0;
        float y1 = c1[reg] + bm1;
        float u0 = 1.5957691216057308f * (y0 + 0.044715f * y0 * y0 * y0);
        float u1 = 1.5957691216057308f * (y1 + 0.044715f * y1 * y1 * y1);
        float t0 = 1.f - 2.f / (1.f + __expf(u0));
        float t1 = 1.f - 2.f / (1.f + __expf(u1));
        y0 = 0.5f * y0 * (1.f + t0);
        y1 = 0.5f * y1 * (1.f + t1);
        float eo0 = e[(size_t)er * DE + m];
        float eo1 = e[(size_t)er * DE + m + 16];
        y0 += eo0;
        y1 += eo1;
        float s = y0 + y1, sq = y0 * y0 + y1 * y1;
#pragma unroll
        for (int off = 1; off < 16; off <<= 1) {
            s += __shfl_xor(s, off, 16);
            sq += __shfl_xor(sq, off, 16);
        }
        float mu = s * (1.f / 32.f);
        float var = sq * (1.f / 32.f) - mu * mu;
        float inv = rsqrtf(var + 1e-5f);
        float z0 = (y0 - mu) * inv * g0 + bb0;
        float z1 = (y1 - mu) * inv * g1 + bb1;
        e[(size_t)er * DE + m] = z0;
        e[(size_t)er * DE + m + 16] = z1;
        if (do_bias) {
            // next-layer edge bias: bias[h] = sum_c e_new[c] * We_next[c][h]
            float p0 = z0 * wn0.x + z1 * wn1.x;
            float p1 = z0 * wn0.y + z1 * wn1.y;
            float p2 = z0 * wn0.z + z1 * wn1.z;
            float p3 = z0 * wn0.w + z1 * wn1.w;
#pragma unroll
            for (int off = 1; off < 16; off <<= 1) {
                p0 += __shfl_xor(p0, off, 16);
                p1 += __shfl_xor(p1, off, 16);
                p2 += __shfl_xor(p2, off, 16);
                p3 += __shfl_xor(p3, off, 16);
            }
            if (m < 4) {
                int rk = rank[er];
                float bsel = (m == 0) ? p0 : (m == 1) ? p1 : (m == 2) ? p2 : p3;
                ebias_s[rk * H + m] = bsel;
            }
        }
    }
}

extern "C" void kernel_launch(void* const* d_in, const int* in_sizes, int n_in,
                              void* d_out, int out_size, void* d_ws, size_t ws_size,
                              hipStream_t stream) {
    const float* node_features = (const float*)d_in[0];
    float* e = (float*)d_in[1];     // updated in place; harness restores inputs
    const int* edge_index = (const int*)d_in[2];
    const int* src = edge_index;
    const int* dst = edge_index + NE;
    const float* Wq = (const float*)d_in[3];
    const float* Wk = (const float*)d_in[4];
    const float* Wv = (const float*)d_in[5];
    const float* Wo = (const float*)d_in[6];
    const float* We = (const float*)d_in[7];
    const float* Wem = (const float*)d_in[8];
    const float* bem = (const float*)d_in[9];
    const float* gn = (const float*)d_in[10];
    const float* bn = (const float*)d_in[11];
    const float* ge = (const float*)d_in[12];
    const float* be = (const float*)d_in[13];

    float* h = (float*)d_out;       // h lives in d_out

    float* ws = (float*)d_ws;
    float* q = ws;                                       // N*D f32
    unsigned int* kv = (unsigned int*)(q + NN * D);      // N*D u32 (packed bf16 k|v)
    float* agg = (float*)(kv + NN * D);                  // N*D f32
    float* ebias_s = agg + NN * D;                       // E*H f32 (sorted order)
    int* offsets = (int*)(ebias_s + (size_t)NE * H);     // NN
    int* cursor = offsets + NN;                          // NN
    int* bsum = cursor + NN;                             // 64
    int* sorted_src = bsum + 64;                         // NE (+pad)
    int* rank = sorted_src + NE + 64;                    // NE
    unsigned short* Wt = (unsigned short*)(rank + NE);   // L*32*160 bf16
    unsigned short* hb = Wt + L * 32 * 160;              // N*D bf16

    const int NB = (NN + 1023) / 1024;

    // ---- CSR build + preconverts (inputs constant; rebuilt every launch) ----
    hipMemsetAsync(cursor, 0, NN * sizeof(int), stream);
    deg_kernel<<<(NE + 255) / 256, 256, 0, stream>>>(dst, cursor);
    block_sum_kernel<<<NB, 256, 0, stream>>>(cursor, bsum);
    scan_bsum_kernel<<<1, 64, 0, stream>>>(bsum, NB);
    scan_block_kernel<<<NB, 256, 0, stream>>>(cursor, bsum, offsets);
    hipMemsetAsync(cursor, 0, NN * sizeof(int), stream);
    scatter_kernel<<<(NE + 255) / 256, 256, 0, stream>>>(src, dst, offsets, cursor,
                                                         sorted_src, rank);
    wconv_kernel<<<(L * 32 * 160 + 255) / 256, 256, 0, stream>>>(Wem, Wt);
    hconv_kernel<<<(NN * D + 255) / 256, 256, 0, stream>>>(node_features, h, hb);
    // layer-0 edge bias (layers 1,2 biases are produced by edge_update's epilogue)
    ebias_kernel<<<(NE * H + 255) / 256, 256, 0, stream>>>(e, We, rank, ebias_s);

    for (int layer = 0; layer < L; layer++) {
        const float* Wq_l = Wq + layer * D * D;
        const float* Wk_l = Wk + layer * D * D;
        const float* Wv_l = Wv + layer * D * D;
        const float* Wo_l = Wo + layer * D * D;
        const unsigned short* Wt_l = Wt + layer * 32 * 160;
        const float* bem_l = bem + layer * DE;
        const float* gn_l = gn + layer * D;
        const float* bn_l = bn + layer * D;
        const float* ge_l = ge + layer * DE;
        const float* be_l = be + layer * DE;
        int do_bias = (layer < L - 1);
        const float* We_next = We + (do_bias ? (layer + 1) : layer) * DE * H;

        qkv_kernel<<<NN / 16, dim3(64, 4), 0, stream>>>(h, Wq_l, Wk_l, Wv_l, q, kv);
        attn_kernel<<<NN / 4, dim3(64, 4), 0, stream>>>(q, kv, ebias_s, sorted_src,
                                                        offsets, agg);
        node_update_kernel<<<NN / 16, dim3(64, 4), 0, stream>>>(h, agg, Wo_l,
                                                                gn_l, bn_l, hb);
        edge_update_mfma_kernel<<<NE / 64, 256, 0, stream>>>(hb, e, src, dst, Wt_l,
                                                             bem_l, ge_l, be_l,
                                                             We_next, rank, ebias_s,
                                                             do_bias);
    }
}

// Round 6
// 1538.377 us; speedup vs baseline: 5.3702x; 1.0737x over previous
//
#include <hip/hip_runtime.h>
#include <hip/hip_bf16.h>
#include <math.h>

#define NN 50000
#define NE 1600000
#define D 64
#define DE 32
#define H 4
#define DH 16
#define L 3

typedef __attribute__((ext_vector_type(8))) short bf16x8;
typedef __attribute__((ext_vector_type(4))) float f32x4;

__device__ __forceinline__ short f2b(float f) {
    __hip_bfloat16 h = __float2bfloat16(f);
    short s;
    __builtin_memcpy(&s, &h, 2);
    return s;
}
__device__ __forceinline__ float b2f(unsigned short u) {
    unsigned int x = ((unsigned int)u) << 16;
    float f; __builtin_memcpy(&f, &x, 4); return f;
}
__device__ __forceinline__ float b2f_lo(unsigned int p) {
    unsigned int x = p << 16;
    float f; __builtin_memcpy(&f, &x, 4); return f;
}
__device__ __forceinline__ float b2f_hi(unsigned int p) {
    unsigned int x = p & 0xffff0000u;
    float f; __builtin_memcpy(&f, &x, 4); return f;
}

// ======================= CSR build (per launch) =======================

__global__ void deg_kernel(const int* __restrict__ dst, int* __restrict__ cnt) {
    int e = blockIdx.x * 256 + threadIdx.x;
    if (e >= NE) return;
    atomicAdd(&cnt[dst[e]], 1);
}

__global__ void block_sum_kernel(const int* __restrict__ cnt, int* __restrict__ bsum) {
    int b = blockIdx.x, t = threadIdx.x;
    int base = b * 1024 + t * 4;
    int s = 0;
#pragma unroll
    for (int i = 0; i < 4; i++) { int idx = base + i; if (idx < NN) s += cnt[idx]; }
#pragma unroll
    for (int off = 32; off; off >>= 1) s += __shfl_down(s, off);
    __shared__ int wsum[4];
    if ((t & 63) == 0) wsum[t >> 6] = s;
    __syncthreads();
    if (t == 0) bsum[b] = wsum[0] + wsum[1] + wsum[2] + wsum[3];
}

__global__ void scan_bsum_kernel(int* __restrict__ bsum, int nb) {
    if (blockIdx.x == 0 && threadIdx.x == 0) {
        int run = 0;
        for (int i = 0; i < nb; i++) { int c = bsum[i]; bsum[i] = run; run += c; }
    }
}

__global__ void scan_block_kernel(const int* __restrict__ cnt, const int* __restrict__ bsum,
                                  int* __restrict__ offsets) {
    int b = blockIdx.x, t = threadIdx.x;
    int base = b * 1024 + t * 4;
    int v[4]; int s = 0;
#pragma unroll
    for (int i = 0; i < 4; i++) { int idx = base + i; v[i] = (idx < NN) ? cnt[idx] : 0; s += v[i]; }
    int lane = t & 63, w = t >> 6;
    int x = s;
#pragma unroll
    for (int off = 1; off < 64; off <<= 1) {
        int y = __shfl_up(x, off);
        if (lane >= off) x += y;
    }
    __shared__ int wsum[4];
    if (lane == 63) wsum[w] = x;
    __syncthreads();
    int woff = 0;
    for (int i = 0; i < w; i++) woff += wsum[i];
    int run = bsum[b] + woff + x - s;
#pragma unroll
    for (int i = 0; i < 4; i++) {
        int idx = base + i;
        if (idx < NN) offsets[idx] = run;
        run += v[i];
    }
}

__global__ void scatter_kernel(const int* __restrict__ src, const int* __restrict__ dst,
                               const int* __restrict__ offsets,
                               int* __restrict__ cursor,
                               int* __restrict__ sorted_src, int* __restrict__ rank) {
    int e = blockIdx.x * 256 + threadIdx.x;
    if (e >= NE) return;
    int d0 = dst[e];
    int pos = atomicAdd(&cursor[d0], 1);
    int position = offsets[d0] + pos;
    sorted_src[position] = src[e];
    rank[e] = position;
}

// ---- Wem[L][160][32] fp32 -> Wt[L][32][160] bf16 (transposed) ----
__global__ void wconv_kernel(const float* __restrict__ Wem, unsigned short* __restrict__ Wt) {
    int t = blockIdx.x * 256 + threadIdx.x;
    if (t >= L * 32 * 160) return;
    int l = t / 5120;
    int r = t % 5120;
    int n = r / 160;
    int k = r % 160;
    Wt[t] = (unsigned short)f2b(Wem[l * 5120 + k * 32 + n]);
}

// ---- h = node_features (fp32) + hb = bf16(node_features) ----
__global__ void hconv_kernel(const float* __restrict__ nf, float* __restrict__ h,
                             unsigned short* __restrict__ hb) {
    int t = blockIdx.x * 256 + threadIdx.x;
    if (t >= NN * D) return;
    float x = nf[t];
    h[t] = x;
    hb[t] = (unsigned short)f2b(x);
}

// ======================= per-layer kernels =======================

// ---- q = (h@Wq)*0.25 ; kv = pack(bf16(k), bf16(v)) ; 16 nodes/block ----
__global__ void qkv_kernel(const float* __restrict__ h,
                           const float* __restrict__ Wq,
                           const float* __restrict__ Wk,
                           const float* __restrict__ Wv,
                           float* __restrict__ q, unsigned int* __restrict__ kv) {
    __shared__ float sW[3 * 4096];   // 48 KB
    __shared__ float sh[16][D];
    int col = threadIdx.x;           // 0..63
    int wv = threadIdx.y;            // 0..3
    int tid = wv * 64 + col;
    int base = blockIdx.x * 16;
    for (int i = tid; i < 4096; i += 256) {
        sW[i] = Wq[i]; sW[4096 + i] = Wk[i]; sW[8192 + i] = Wv[i];
    }
    for (int i = tid; i < 16 * D; i += 256) {
        int n = base + (i >> 6);
        sh[i >> 6][i & 63] = h[n * D + (i & 63)];
    }
    __syncthreads();
#pragma unroll
    for (int it = 0; it < 4; it++) {
        int ln = wv * 4 + it;
        int node = base + ln;
        float aq = 0.f, ak = 0.f, av = 0.f;
#pragma unroll
        for (int kk = 0; kk < D; kk++) {
            float hv = sh[ln][kk];
            aq += hv * sW[kk * D + col];
            ak += hv * sW[4096 + kk * D + col];
            av += hv * sW[8192 + kk * D + col];
        }
        q[node * D + col] = aq * 0.25f;
        unsigned int kb = (unsigned int)(unsigned short)f2b(ak);
        unsigned int vb = (unsigned int)(unsigned short)f2b(av);
        kv[node * D + col] = (vb << 16) | kb;
    }
}

// ---- standalone ebias (layer 0 only), reads pristine fp32 e ----
__global__ void ebias_kernel(const float* __restrict__ e, const float* __restrict__ We,
                             const int* __restrict__ rank, float* __restrict__ ebias_s) {
    int t = blockIdx.x * 256 + threadIdx.x;
    if (t >= NE * H) return;
    int edge = t >> 2;
    int hh = t & 3;
    const float* ep = e + (size_t)edge * DE;
    float bias = 0.f;
#pragma unroll
    for (int i = 0; i < DE; i++) bias += ep[i] * We[i * H + hh];
    ebias_s[rank[edge] * H + hh] = bias;
}

// ---- fused per-dst-node online-softmax attention + aggregation (8-wide) ----
__global__ void attn_kernel(const float* __restrict__ q, const unsigned int* __restrict__ kv,
                            const float* __restrict__ ebias_s,
                            const int* __restrict__ sorted_src,
                            const int* __restrict__ offsets,
                            float* __restrict__ agg) {
    int node = blockIdx.x * 4 + threadIdx.y;
    node = __builtin_amdgcn_readfirstlane(node);
    if (node >= NN) return;
    int lane = threadIdx.x;
    int hh = lane >> 4;
    float qv = q[node * D + lane];
    int beg = offsets[node];
    int end = (node == NN - 1) ? NE : offsets[node + 1];
    float mmax = -INFINITY, den = 0.f, acc = 0.f;
    int i = beg;
    for (; i + 8 <= end; i += 8) {
        int ss[8]; unsigned int kk8[8]; float bb8[8], dd[8];
#pragma unroll
        for (int u = 0; u < 8; u++) ss[u] = sorted_src[i + u];
#pragma unroll
        for (int u = 0; u < 8; u++) kk8[u] = kv[ss[u] * D + lane];
#pragma unroll
        for (int u = 0; u < 8; u++) bb8[u] = ebias_s[(i + u) * H + hh];
#pragma unroll
        for (int u = 0; u < 8; u++) dd[u] = qv * b2f_lo(kk8[u]);
#pragma unroll
        for (int off = 1; off < 16; off <<= 1) {
#pragma unroll
            for (int u = 0; u < 8; u++) dd[u] += __shfl_xor(dd[u], off, 16);
        }
        float nm = mmax;
#pragma unroll
        for (int u = 0; u < 8; u++) { dd[u] += bb8[u]; nm = fmaxf(nm, dd[u]); }
        float scale = __expf(mmax - nm);
        float ps = 0.f, av = 0.f;
#pragma unroll
        for (int u = 0; u < 8; u++) {
            float p = __expf(dd[u] - nm);
            ps += p;
            av += p * b2f_hi(kk8[u]);
        }
        den = den * scale + ps;
        acc = acc * scale + av;
        mmax = nm;
    }
    for (; i < end; i++) {
        int s = sorted_src[i];
        unsigned int kvv = kv[s * D + lane];
        float b = ebias_s[i * H + hh];
        float dot = qv * b2f_lo(kvv);
#pragma unroll
        for (int off = 1; off < 16; off <<= 1) dot += __shfl_xor(dot, off, 16);
        float score = dot + b;
        float nm = fmaxf(mmax, score);
        float scale = __expf(mmax - nm);
        float p = __expf(score - nm);
        den = den * scale + p;
        acc = acc * scale + p * b2f_hi(kvv);
        mmax = nm;
    }
    agg[node * D + lane] = acc / (den + 1e-9f);
}

// ---- h = LN(h + agg @ Wo) + bf16 shadow ; 16 nodes/block ----
__global__ void node_update_kernel(float* __restrict__ h, const float* __restrict__ agg,
                                   const float* __restrict__ Wo,
                                   const float* __restrict__ gn,
                                   const float* __restrict__ bn,
                                   unsigned short* __restrict__ hb) {
    __shared__ float sWo[4096];      // 16 KB
    __shared__ float sagg[16][D];
    int col = threadIdx.x, wv = threadIdx.y;
    int tid = wv * 64 + col;
    int base = blockIdx.x * 16;
    for (int i = tid; i < 4096; i += 256) sWo[i] = Wo[i];
    for (int i = tid; i < 16 * D; i += 256) {
        int n = base + (i >> 6);
        sagg[i >> 6][i & 63] = agg[n * D + (i & 63)];
    }
    __syncthreads();
    float gcol = gn[col], bcol = bn[col];
#pragma unroll
    for (int it = 0; it < 4; it++) {
        int ln = wv * 4 + it;
        int node = base + ln;
        float acc = 0.f;
#pragma unroll
        for (int kk = 0; kk < D; kk++) acc += sagg[ln][kk] * sWo[kk * D + col];
        float x = h[node * D + col] + acc;
        float sum = x, sq = x * x;
#pragma unroll
        for (int off = 32; off; off >>= 1) {
            sum += __shfl_xor(sum, off);
            sq += __shfl_xor(sq, off);
        }
        float mu = sum * (1.f / 64.f);
        float var = sq * (1.f / 64.f) - mu * mu;
        float out = (x - mu) * rsqrtf(var + 1e-5f) * gcol + bcol;
        h[node * D + col] = out;
        hb[node * D + col] = (unsigned short)f2b(out);
    }
}

// ---- e = LN(e + gelu([h[src]|h[dst]|e] @ Wem + bem)) via bf16 MFMA.
// e state: layer 0 reads pristine fp32 e (d_in[1]); all layers write bf16 eb;
// layers >0 read bf16 eb. Next-layer ebias fused into the epilogue.
__global__ void edge_update_mfma_kernel(const unsigned short* __restrict__ hb,
                                        const float* __restrict__ e32,       // fp32 e (layer 0)
                                        unsigned short* __restrict__ eb,     // bf16 e state
                                        const int* __restrict__ src, const int* __restrict__ dst,
                                        const unsigned short* __restrict__ Wt,   // [32][160] bf16
                                        const float* __restrict__ bem,
                                        const float* __restrict__ ge,
                                        const float* __restrict__ be,
                                        const float* __restrict__ We_next,       // [32][4]
                                        const int* __restrict__ rank,
                                        float* __restrict__ ebias_s,
                                        int use_fp32_e, int do_bias) {
    int wave = threadIdx.x >> 6;
    int lane = threadIdx.x & 63;
    int we = blockIdx.x * 64 + wave * 16;
    int m = lane & 15;
    int quad = lane >> 4;
    int edge_m = we + m;
    int s_idx = src[edge_m], d_idx = dst[edge_m];

    const unsigned short* as = hb + (size_t)s_idx * D + quad * 8;
    const unsigned short* ad = hb + (size_t)d_idx * D + quad * 8;
    const unsigned short* w0 = Wt + m * 160 + quad * 8;

    f32x4 c0 = {0.f, 0.f, 0.f, 0.f};
    f32x4 c1 = {0.f, 0.f, 0.f, 0.f};

#pragma unroll
    for (int ks = 0; ks < 4; ks++) {
        const unsigned short* ap = (ks < 2) ? as : ad;
        bf16x8 a = *(const bf16x8*)(ap + (ks & 1) * 32);
        bf16x8 b0 = *(const bf16x8*)(w0 + ks * 32);
        bf16x8 b1 = *(const bf16x8*)(w0 + ks * 32 + 16 * 160);
        c0 = __builtin_amdgcn_mfma_f32_16x16x32_bf16(a, b0, c0, 0, 0, 0);
        c1 = __builtin_amdgcn_mfma_f32_16x16x32_bf16(a, b1, c1, 0, 0, 0);
    }
    {
        bf16x8 a;
        if (use_fp32_e) {
            const float* ae = e32 + (size_t)edge_m * DE + quad * 8;
            float4 x0 = *(const float4*)(ae);
            float4 x1 = *(const float4*)(ae + 4);
            a[0] = f2b(x0.x); a[1] = f2b(x0.y); a[2] = f2b(x0.z); a[3] = f2b(x0.w);
            a[4] = f2b(x1.x); a[5] = f2b(x1.y); a[6] = f2b(x1.z); a[7] = f2b(x1.w);
        } else {
            a = *(const bf16x8*)(eb + (size_t)edge_m * DE + quad * 8);
        }
        bf16x8 b0 = *(const bf16x8*)(w0 + 4 * 32);
        bf16x8 b1 = *(const bf16x8*)(w0 + 4 * 32 + 16 * 160);
        c0 = __builtin_amdgcn_mfma_f32_16x16x32_bf16(a, b0, c0, 0, 0, 0);
        c1 = __builtin_amdgcn_mfma_f32_16x16x32_bf16(a, b1, c1, 0, 0, 0);
    }

    // epilogue: C/D layout col=lane&15, row=quad*4+reg
    float bm0 = bem[m], bm1 = bem[m + 16];
    float g0 = ge[m], g1 = ge[m + 16];
    float bb0 = be[m], bb1 = be[m + 16];
    float4 wn0 = {0, 0, 0, 0}, wn1 = {0, 0, 0, 0};
    if (do_bias) {
        wn0 = *(const float4*)(We_next + m * 4);
        wn1 = *(const float4*)(We_next + (m + 16) * 4);
    }
#pragma unroll
    for (int reg = 0; reg < 4; reg++) {
        int er = we + quad * 4 + reg;
        float y0 = c0[reg] + bm0;
        float y1 = c1[reg] + bm1;
        float u0 = 1.5957691216057308f * (y0 + 0.044715f * y0 * y0 * y0);
        float u1 = 1.5957691216057308f * (y1 + 0.044715f * y1 * y1 * y1);
        float t0 = 1.f - 2.f / (1.f + __expf(u0));
        float t1 = 1.f - 2.f / (1.f + __expf(u1));
        y0 = 0.5f * y0 * (1.f + t0);
        y1 = 0.5f * y1 * (1.f + t1);
        float eo0, eo1;
        if (use_fp32_e) {
            eo0 = e32[(size_t)er * DE + m];
            eo1 = e32[(size_t)er * DE + m + 16];
        } else {
            eo0 = b2f(eb[(size_t)er * DE + m]);
            eo1 = b2f(eb[(size_t)er * DE + m + 16]);
        }
        y0 += eo0;
        y1 += eo1;
        float s = y0 + y1, sq = y0 * y0 + y1 * y1;
#pragma unroll
        for (int off = 1; off < 16; off <<= 1) {
            s += __shfl_xor(s, off, 16);
            sq += __shfl_xor(sq, off, 16);
        }
        float mu = s * (1.f / 32.f);
        float var = sq * (1.f / 32.f) - mu * mu;
        float inv = rsqrtf(var + 1e-5f);
        float z0 = (y0 - mu) * inv * g0 + bb0;
        float z1 = (y1 - mu) * inv * g1 + bb1;
        eb[(size_t)er * DE + m] = (unsigned short)f2b(z0);
        eb[(size_t)er * DE + m + 16] = (unsigned short)f2b(z1);
        if (do_bias) {
            float p0 = z0 * wn0.x + z1 * wn1.x;
            float p1 = z0 * wn0.y + z1 * wn1.y;
            float p2 = z0 * wn0.z + z1 * wn1.z;
            float p3 = z0 * wn0.w + z1 * wn1.w;
#pragma unroll
            for (int off = 1; off < 16; off <<= 1) {
                p0 += __shfl_xor(p0, off, 16);
                p1 += __shfl_xor(p1, off, 16);
                p2 += __shfl_xor(p2, off, 16);
                p3 += __shfl_xor(p3, off, 16);
            }
            if (m < 4) {
                int rk = rank[er];
                float bsel = (m == 0) ? p0 : (m == 1) ? p1 : (m == 2) ? p2 : p3;
                ebias_s[rk * H + m] = bsel;
            }
        }
    }
}

extern "C" void kernel_launch(void* const* d_in, const int* in_sizes, int n_in,
                              void* d_out, int out_size, void* d_ws, size_t ws_size,
                              hipStream_t stream) {
    const float* node_features = (const float*)d_in[0];
    const float* e = (const float*)d_in[1];   // pristine fp32 e (read-only)
    const int* edge_index = (const int*)d_in[2];
    const int* src = edge_index;
    const int* dst = edge_index + NE;
    const float* Wq = (const float*)d_in[3];
    const float* Wk = (const float*)d_in[4];
    const float* Wv = (const float*)d_in[5];
    const float* Wo = (const float*)d_in[6];
    const float* We = (const float*)d_in[7];
    const float* Wem = (const float*)d_in[8];
    const float* bem = (const float*)d_in[9];
    const float* gn = (const float*)d_in[10];
    const float* bn = (const float*)d_in[11];
    const float* ge = (const float*)d_in[12];
    const float* be = (const float*)d_in[13];

    float* h = (float*)d_out;       // h lives in d_out

    float* ws = (float*)d_ws;
    float* q = ws;                                       // N*D f32
    unsigned int* kv = (unsigned int*)(q + NN * D);      // N*D u32 (packed bf16 k|v)
    float* agg = (float*)(kv + NN * D);                  // N*D f32
    float* ebias_s = agg + NN * D;                       // E*H f32 (sorted order)
    int* offsets = (int*)(ebias_s + (size_t)NE * H);     // NN
    int* cursor = offsets + NN;                          // NN
    int* bsum = cursor + NN;                             // 64
    int* sorted_src = bsum + 64;                         // NE (+pad)
    int* rank = sorted_src + NE + 64;                    // NE
    unsigned short* Wt = (unsigned short*)(rank + NE);   // L*32*160 bf16
    unsigned short* hb = Wt + L * 32 * 160;              // N*D bf16
    unsigned short* eb = hb + NN * D;                    // E*DE bf16 e-state

    const int NB = (NN + 1023) / 1024;

    // ---- CSR build + preconverts (inputs constant; rebuilt every launch) ----
    hipMemsetAsync(cursor, 0, NN * sizeof(int), stream);
    deg_kernel<<<(NE + 255) / 256, 256, 0, stream>>>(dst, cursor);
    block_sum_kernel<<<NB, 256, 0, stream>>>(cursor, bsum);
    scan_bsum_kernel<<<1, 64, 0, stream>>>(bsum, NB);
    scan_block_kernel<<<NB, 256, 0, stream>>>(cursor, bsum, offsets);
    hipMemsetAsync(cursor, 0, NN * sizeof(int), stream);
    scatter_kernel<<<(NE + 255) / 256, 256, 0, stream>>>(src, dst, offsets, cursor,
                                                         sorted_src, rank);
    wconv_kernel<<<(L * 32 * 160 + 255) / 256, 256, 0, stream>>>(Wem, Wt);
    hconv_kernel<<<(NN * D + 255) / 256, 256, 0, stream>>>(node_features, h, hb);
    // layer-0 edge bias (layers 1,2 biases produced by edge_update's epilogue)
    ebias_kernel<<<(NE * H + 255) / 256, 256, 0, stream>>>(e, We, rank, ebias_s);

    for (int layer = 0; layer < L; layer++) {
        const float* Wq_l = Wq + layer * D * D;
        const float* Wk_l = Wk + layer * D * D;
        const float* Wv_l = Wv + layer * D * D;
        const float* Wo_l = Wo + layer * D * D;
        const unsigned short* Wt_l = Wt + layer * 32 * 160;
        const float* bem_l = bem + layer * DE;
        const float* gn_l = gn + layer * D;
        const float* bn_l = bn + layer * D;
        const float* ge_l = ge + layer * DE;
        const float* be_l = be + layer * DE;
        int do_bias = (layer < L - 1);
        const float* We_next = We + (do_bias ? (layer + 1) : layer) * DE * H;
        int use_fp32_e = (layer == 0);

        qkv_kernel<<<NN / 16, dim3(64, 4), 0, stream>>>(h, Wq_l, Wk_l, Wv_l, q, kv);
        attn_kernel<<<NN / 4, dim3(64, 4), 0, stream>>>(q, kv, ebias_s, sorted_src,
                                                        offsets, agg);
        node_update_kernel<<<NN / 16, dim3(64, 4), 0, stream>>>(h, agg, Wo_l,
                                                                gn_l, bn_l, hb);
        edge_update_mfma_kernel<<<NE / 64, 256, 0, stream>>>(hb, e, eb, src, dst, Wt_l,
                                                             bem_l, ge_l, be_l,
                                                             We_next, rank, ebias_s,
                                                             use_fp32_e, do_bias);
    }
}

// Round 7
// 1408.609 us; speedup vs baseline: 5.8649x; 1.0921x over previous
//
#include <hip/hip_runtime.h>
#include <hip/hip_bf16.h>
#include <math.h>

#define NN 50000
#define NE 1600000
#define D 64
#define DE 32
#define H 4
#define DH 16
#define L 3

typedef __attribute__((ext_vector_type(8))) short bf16x8;
typedef __attribute__((ext_vector_type(4))) float f32x4;

__device__ __forceinline__ short f2b(float f) {
    __hip_bfloat16 h = __float2bfloat16(f);
    short s;
    __builtin_memcpy(&s, &h, 2);
    return s;
}
__device__ __forceinline__ float b2f(unsigned short u) {
    unsigned int x = ((unsigned int)u) << 16;
    float f; __builtin_memcpy(&f, &x, 4); return f;
}
__device__ __forceinline__ float b2f_lo(unsigned int p) {
    unsigned int x = p << 16;
    float f; __builtin_memcpy(&f, &x, 4); return f;
}
__device__ __forceinline__ float b2f_hi(unsigned int p) {
    unsigned int x = p & 0xffff0000u;
    float f; __builtin_memcpy(&f, &x, 4); return f;
}

// ======================= CSR build (per launch) =======================

__global__ void deg_kernel(const int* __restrict__ dst, int* __restrict__ cnt) {
    int e = blockIdx.x * 256 + threadIdx.x;
    if (e >= NE) return;
    atomicAdd(&cnt[dst[e]], 1);
}

__global__ void block_sum_kernel(const int* __restrict__ cnt, int* __restrict__ bsum) {
    int b = blockIdx.x, t = threadIdx.x;
    int base = b * 1024 + t * 4;
    int s = 0;
#pragma unroll
    for (int i = 0; i < 4; i++) { int idx = base + i; if (idx < NN) s += cnt[idx]; }
#pragma unroll
    for (int off = 32; off; off >>= 1) s += __shfl_down(s, off);
    __shared__ int wsum[4];
    if ((t & 63) == 0) wsum[t >> 6] = s;
    __syncthreads();
    if (t == 0) bsum[b] = wsum[0] + wsum[1] + wsum[2] + wsum[3];
}

__global__ void scan_bsum_kernel(int* __restrict__ bsum, int nb) {
    if (blockIdx.x == 0 && threadIdx.x == 0) {
        int run = 0;
        for (int i = 0; i < nb; i++) { int c = bsum[i]; bsum[i] = run; run += c; }
    }
}

__global__ void scan_block_kernel(const int* __restrict__ cnt, const int* __restrict__ bsum,
                                  int* __restrict__ offsets) {
    int b = blockIdx.x, t = threadIdx.x;
    int base = b * 1024 + t * 4;
    int v[4]; int s = 0;
#pragma unroll
    for (int i = 0; i < 4; i++) { int idx = base + i; v[i] = (idx < NN) ? cnt[idx] : 0; s += v[i]; }
    int lane = t & 63, w = t >> 6;
    int x = s;
#pragma unroll
    for (int off = 1; off < 64; off <<= 1) {
        int y = __shfl_up(x, off);
        if (lane >= off) x += y;
    }
    __shared__ int wsum[4];
    if (lane == 63) wsum[w] = x;
    __syncthreads();
    int woff = 0;
    for (int i = 0; i < w; i++) woff += wsum[i];
    int run = bsum[b] + woff + x - s;
#pragma unroll
    for (int i = 0; i < 4; i++) {
        int idx = base + i;
        if (idx < NN) offsets[idx] = run;
        run += v[i];
    }
}

__global__ void scatter_kernel(const int* __restrict__ src, const int* __restrict__ dst,
                               const int* __restrict__ offsets,
                               int* __restrict__ cursor,
                               int* __restrict__ sorted_eid,
                               int* __restrict__ sorted_src,
                               int* __restrict__ sorted_dst) {
    int e = blockIdx.x * 256 + threadIdx.x;
    if (e >= NE) return;
    int d0 = dst[e];
    int pos = atomicAdd(&cursor[d0], 1);
    int position = offsets[d0] + pos;
    sorted_eid[position] = e;
    sorted_src[position] = src[e];
    sorted_dst[position] = d0;
}

// ---- permute pristine fp32 e into dst-sorted bf16 eb_s ----
__global__ void eperm_kernel(const float* __restrict__ e32, const int* __restrict__ sorted_eid,
                             unsigned short* __restrict__ eb_s) {
    int t = blockIdx.x * 256 + threadIdx.x;
    if (t >= NE * 4) return;
    int p = t >> 2;
    int c = (t & 3) * 8;
    int eid = sorted_eid[p];
    const float* ep = e32 + (size_t)eid * DE + c;
    float4 x0 = *(const float4*)(ep);
    float4 x1 = *(const float4*)(ep + 4);
    unsigned short* op = eb_s + (size_t)p * DE + c;
    op[0] = (unsigned short)f2b(x0.x); op[1] = (unsigned short)f2b(x0.y);
    op[2] = (unsigned short)f2b(x0.z); op[3] = (unsigned short)f2b(x0.w);
    op[4] = (unsigned short)f2b(x1.x); op[5] = (unsigned short)f2b(x1.y);
    op[6] = (unsigned short)f2b(x1.z); op[7] = (unsigned short)f2b(x1.w);
}

// ---- Wem[L][160][32] fp32 -> Wt[L][32][160] bf16 (transposed) ----
__global__ void wconv_kernel(const float* __restrict__ Wem, unsigned short* __restrict__ Wt) {
    int t = blockIdx.x * 256 + threadIdx.x;
    if (t >= L * 32 * 160) return;
    int l = t / 5120;
    int r = t % 5120;
    int n = r / 160;
    int k = r % 160;
    Wt[t] = (unsigned short)f2b(Wem[l * 5120 + k * 32 + n]);
}

// ---- h = node_features (fp32) + hb = bf16(node_features) ----
__global__ void hconv_kernel(const float* __restrict__ nf, float* __restrict__ h,
                             unsigned short* __restrict__ hb) {
    int t = blockIdx.x * 256 + threadIdx.x;
    if (t >= NN * D) return;
    float x = nf[t];
    h[t] = x;
    hb[t] = (unsigned short)f2b(x);
}

// ---- layer-0 edge bias from sorted bf16 e-state (contiguous) ----
__global__ void ebias0_kernel(const unsigned short* __restrict__ eb_s,
                              const float* __restrict__ We,
                              float* __restrict__ ebias_s) {
    int t = blockIdx.x * 256 + threadIdx.x;
    if (t >= NE * H) return;
    int p = t >> 2;
    int hh = t & 3;
    const unsigned short* ep = eb_s + (size_t)p * DE;
    float bias = 0.f;
#pragma unroll
    for (int i = 0; i < DE; i++) bias += b2f(ep[i]) * We[i * H + hh];
    ebias_s[t] = bias;
}

// ======================= per-layer kernels =======================

// ---- q = (h@Wq)*0.25 ; kv = pack(bf16(k), bf16(v)) ; 16 nodes/block ----
__global__ void qkv_kernel(const float* __restrict__ h,
                           const float* __restrict__ Wq,
                           const float* __restrict__ Wk,
                           const float* __restrict__ Wv,
                           float* __restrict__ q, unsigned int* __restrict__ kv) {
    __shared__ float sW[3 * 4096];   // 48 KB
    __shared__ float sh[16][D];
    int col = threadIdx.x;           // 0..63
    int wv = threadIdx.y;            // 0..3
    int tid = wv * 64 + col;
    int base = blockIdx.x * 16;
    for (int i = tid; i < 4096; i += 256) {
        sW[i] = Wq[i]; sW[4096 + i] = Wk[i]; sW[8192 + i] = Wv[i];
    }
    for (int i = tid; i < 16 * D; i += 256) {
        int n = base + (i >> 6);
        sh[i >> 6][i & 63] = h[n * D + (i & 63)];
    }
    __syncthreads();
#pragma unroll
    for (int it = 0; it < 4; it++) {
        int ln = wv * 4 + it;
        int node = base + ln;
        float aq = 0.f, ak = 0.f, av = 0.f;
#pragma unroll
        for (int kk = 0; kk < D; kk++) {
            float hv = sh[ln][kk];
            aq += hv * sW[kk * D + col];
            ak += hv * sW[4096 + kk * D + col];
            av += hv * sW[8192 + kk * D + col];
        }
        q[node * D + col] = aq * 0.25f;
        unsigned int kb = (unsigned int)(unsigned short)f2b(ak);
        unsigned int vb = (unsigned int)(unsigned short)f2b(av);
        kv[node * D + col] = (vb << 16) | kb;
    }
}

// ---- fused per-dst-node online-softmax attention + aggregation (8-wide) ----
__global__ void attn_kernel(const float* __restrict__ q, const unsigned int* __restrict__ kv,
                            const float* __restrict__ ebias_s,
                            const int* __restrict__ sorted_src,
                            const int* __restrict__ offsets,
                            float* __restrict__ agg) {
    int node = blockIdx.x * 4 + threadIdx.y;
    node = __builtin_amdgcn_readfirstlane(node);
    if (node >= NN) return;
    int lane = threadIdx.x;
    int hh = lane >> 4;
    float qv = q[node * D + lane];
    int beg = offsets[node];
    int end = (node == NN - 1) ? NE : offsets[node + 1];
    float mmax = -INFINITY, den = 0.f, acc = 0.f;
    int i = beg;
    for (; i + 8 <= end; i += 8) {
        int ss[8]; unsigned int kk8[8]; float bb8[8], dd[8];
#pragma unroll
        for (int u = 0; u < 8; u++) ss[u] = sorted_src[i + u];
#pragma unroll
        for (int u = 0; u < 8; u++) kk8[u] = kv[ss[u] * D + lane];
#pragma unroll
        for (int u = 0; u < 8; u++) bb8[u] = ebias_s[(i + u) * H + hh];
#pragma unroll
        for (int u = 0; u < 8; u++) dd[u] = qv * b2f_lo(kk8[u]);
#pragma unroll
        for (int off = 1; off < 16; off <<= 1) {
#pragma unroll
            for (int u = 0; u < 8; u++) dd[u] += __shfl_xor(dd[u], off, 16);
        }
        float nm = mmax;
#pragma unroll
        for (int u = 0; u < 8; u++) { dd[u] += bb8[u]; nm = fmaxf(nm, dd[u]); }
        float scale = __expf(mmax - nm);
        float ps = 0.f, av = 0.f;
#pragma unroll
        for (int u = 0; u < 8; u++) {
            float p = __expf(dd[u] - nm);
            ps += p;
            av += p * b2f_hi(kk8[u]);
        }
        den = den * scale + ps;
        acc = acc * scale + av;
        mmax = nm;
    }
    for (; i < end; i++) {
        int s = sorted_src[i];
        unsigned int kvv = kv[s * D + lane];
        float b = ebias_s[i * H + hh];
        float dot = qv * b2f_lo(kvv);
#pragma unroll
        for (int off = 1; off < 16; off <<= 1) dot += __shfl_xor(dot, off, 16);
        float score = dot + b;
        float nm = fmaxf(mmax, score);
        float scale = __expf(mmax - nm);
        float p = __expf(score - nm);
        den = den * scale + p;
        acc = acc * scale + p * b2f_hi(kvv);
        mmax = nm;
    }
    agg[node * D + lane] = acc / (den + 1e-9f);
}

// ---- h = LN(h + agg @ Wo) + bf16 shadow ; 16 nodes/block ----
__global__ void node_update_kernel(float* __restrict__ h, const float* __restrict__ agg,
                                   const float* __restrict__ Wo,
                                   const float* __restrict__ gn,
                                   const float* __restrict__ bn,
                                   unsigned short* __restrict__ hb) {
    __shared__ float sWo[4096];      // 16 KB
    __shared__ float sagg[16][D];
    int col = threadIdx.x, wv = threadIdx.y;
    int tid = wv * 64 + col;
    int base = blockIdx.x * 16;
    for (int i = tid; i < 4096; i += 256) sWo[i] = Wo[i];
    for (int i = tid; i < 16 * D; i += 256) {
        int n = base + (i >> 6);
        sagg[i >> 6][i & 63] = agg[n * D + (i & 63)];
    }
    __syncthreads();
    float gcol = gn[col], bcol = bn[col];
#pragma unroll
    for (int it = 0; it < 4; it++) {
        int ln = wv * 4 + it;
        int node = base + ln;
        float acc = 0.f;
#pragma unroll
        for (int kk = 0; kk < D; kk++) acc += sagg[ln][kk] * sWo[kk * D + col];
        float x = h[node * D + col] + acc;
        float sum = x, sq = x * x;
#pragma unroll
        for (int off = 32; off; off >>= 1) {
            sum += __shfl_xor(sum, off);
            sq += __shfl_xor(sq, off);
        }
        float mu = sum * (1.f / 64.f);
        float var = sq * (1.f / 64.f) - mu * mu;
        float out = (x - mu) * rsqrtf(var + 1e-5f) * gcol + bcol;
        h[node * D + col] = out;
        hb[node * D + col] = (unsigned short)f2b(out);
    }
}

// ---- e = LN(e + gelu([h[src]|h[dst]|e] @ Wem + bem)) via bf16 MFMA.
// All edge state in dst-sorted position order: eb_s read/write contiguous,
// next-layer ebias_s written contiguous (no rank scatter).
__global__ void edge_update_mfma_kernel(const unsigned short* __restrict__ hb,
                                        unsigned short* __restrict__ eb_s,
                                        const int* __restrict__ sorted_src,
                                        const int* __restrict__ sorted_dst,
                                        const unsigned short* __restrict__ Wt,   // [32][160] bf16
                                        const float* __restrict__ bem,
                                        const float* __restrict__ ge,
                                        const float* __restrict__ be,
                                        const float* __restrict__ We_next,       // [32][4]
                                        float* __restrict__ ebias_s,
                                        int do_bias) {
    int wave = threadIdx.x >> 6;
    int lane = threadIdx.x & 63;
    int we = blockIdx.x * 64 + wave * 16;       // first sorted position of this wave
    int m = lane & 15;
    int quad = lane >> 4;
    int p_m = we + m;
    int s_idx = sorted_src[p_m], d_idx = sorted_dst[p_m];

    const unsigned short* as = hb + (size_t)s_idx * D + quad * 8;
    const unsigned short* ad = hb + (size_t)d_idx * D + quad * 8;
    const unsigned short* w0 = Wt + m * 160 + quad * 8;

    f32x4 c0 = {0.f, 0.f, 0.f, 0.f};
    f32x4 c1 = {0.f, 0.f, 0.f, 0.f};

#pragma unroll
    for (int ks = 0; ks < 4; ks++) {
        const unsigned short* ap = (ks < 2) ? as : ad;
        bf16x8 a = *(const bf16x8*)(ap + (ks & 1) * 32);
        bf16x8 b0 = *(const bf16x8*)(w0 + ks * 32);
        bf16x8 b1 = *(const bf16x8*)(w0 + ks * 32 + 16 * 160);
        c0 = __builtin_amdgcn_mfma_f32_16x16x32_bf16(a, b0, c0, 0, 0, 0);
        c1 = __builtin_amdgcn_mfma_f32_16x16x32_bf16(a, b1, c1, 0, 0, 0);
    }
    {
        bf16x8 a = *(const bf16x8*)(eb_s + (size_t)p_m * DE + quad * 8);
        bf16x8 b0 = *(const bf16x8*)(w0 + 4 * 32);
        bf16x8 b1 = *(const bf16x8*)(w0 + 4 * 32 + 16 * 160);
        c0 = __builtin_amdgcn_mfma_f32_16x16x32_bf16(a, b0, c0, 0, 0, 0);
        c1 = __builtin_amdgcn_mfma_f32_16x16x32_bf16(a, b1, c1, 0, 0, 0);
    }

    // epilogue: C/D layout col=lane&15, row=quad*4+reg
    float bm0 = bem[m], bm1 = bem[m + 16];
    float g0 = ge[m], g1 = ge[m + 16];
    float bb0 = be[m], bb1 = be[m + 16];
    float4 wn0 = {0, 0, 0, 0}, wn1 = {0, 0, 0, 0};
    if (do_bias) {
        wn0 = *(const float4*)(We_next + m * 4);
        wn1 = *(const float4*)(We_next + (m + 16) * 4);
    }
#pragma unroll
    for (int reg = 0; reg < 4; reg++) {
        int er = we + quad * 4 + reg;            // sorted position of this C-row
        float y0 = c0[reg] + bm0;
        float y1 = c1[reg] + bm1;
        float u0 = 1.5957691216057308f * (y0 + 0.044715f * y0 * y0 * y0);
        float u1 = 1.5957691216057308f * (y1 + 0.044715f * y1 * y1 * y1);
        float t0 = 1.f - 2.f / (1.f + __expf(u0));
        float t1 = 1.f - 2.f / (1.f + __expf(u1));
        y0 = 0.5f * y0 * (1.f + t0);
        y1 = 0.5f * y1 * (1.f + t1);
        float eo0 = b2f(eb_s[(size_t)er * DE + m]);
        float eo1 = b2f(eb_s[(size_t)er * DE + m + 16]);
        y0 += eo0;
        y1 += eo1;
        float s = y0 + y1, sq = y0 * y0 + y1 * y1;
#pragma unroll
        for (int off = 1; off < 16; off <<= 1) {
            s += __shfl_xor(s, off, 16);
            sq += __shfl_xor(sq, off, 16);
        }
        float mu = s * (1.f / 32.f);
        float var = sq * (1.f / 32.f) - mu * mu;
        float inv = rsqrtf(var + 1e-5f);
        float z0 = (y0 - mu) * inv * g0 + bb0;
        float z1 = (y1 - mu) * inv * g1 + bb1;
        eb_s[(size_t)er * DE + m] = (unsigned short)f2b(z0);
        eb_s[(size_t)er * DE + m + 16] = (unsigned short)f2b(z1);
        if (do_bias) {
            float p0 = z0 * wn0.x + z1 * wn1.x;
            float p1 = z0 * wn0.y + z1 * wn1.y;
            float p2 = z0 * wn0.z + z1 * wn1.z;
            float p3 = z0 * wn0.w + z1 * wn1.w;
#pragma unroll
            for (int off = 1; off < 16; off <<= 1) {
                p0 += __shfl_xor(p0, off, 16);
                p1 += __shfl_xor(p1, off, 16);
                p2 += __shfl_xor(p2, off, 16);
                p3 += __shfl_xor(p3, off, 16);
            }
            if (m < 4) {
                float bsel = (m == 0) ? p0 : (m == 1) ? p1 : (m == 2) ? p2 : p3;
                ebias_s[er * H + m] = bsel;   // contiguous by position
            }
        }
    }
}

extern "C" void kernel_launch(void* const* d_in, const int* in_sizes, int n_in,
                              void* d_out, int out_size, void* d_ws, size_t ws_size,
                              hipStream_t stream) {
    const float* node_features = (const float*)d_in[0];
    const float* e = (const float*)d_in[1];   // pristine fp32 e (read-only)
    const int* edge_index = (const int*)d_in[2];
    const int* src = edge_index;
    const int* dst = edge_index + NE;
    const float* Wq = (const float*)d_in[3];
    const float* Wk = (const float*)d_in[4];
    const float* Wv = (const float*)d_in[5];
    const float* Wo = (const float*)d_in[6];
    const float* We = (const float*)d_in[7];
    const float* Wem = (const float*)d_in[8];
    const float* bem = (const float*)d_in[9];
    const float* gn = (const float*)d_in[10];
    const float* bn = (const float*)d_in[11];
    const float* ge = (const float*)d_in[12];
    const float* be = (const float*)d_in[13];

    float* h = (float*)d_out;       // h lives in d_out

    float* ws = (float*)d_ws;
    float* q = ws;                                       // N*D f32
    unsigned int* kv = (unsigned int*)(q + NN * D);      // N*D u32 (packed bf16 k|v)
    float* agg = (float*)(kv + NN * D);                  // N*D f32
    float* ebias_s = agg + NN * D;                       // E*H f32 (sorted order)
    int* offsets = (int*)(ebias_s + (size_t)NE * H);     // NN
    int* cursor = offsets + NN;                          // NN
    int* bsum = cursor + NN;                             // 64
    int* sorted_eid = bsum + 64;                         // NE
    int* sorted_src = sorted_eid + NE;                   // NE
    int* sorted_dst = sorted_src + NE;                   // NE
    unsigned short* Wt = (unsigned short*)(sorted_dst + NE);  // L*32*160 bf16
    unsigned short* hb = Wt + L * 32 * 160;              // N*D bf16
    unsigned short* eb_s = hb + NN * D;                  // E*DE bf16 e-state (sorted)

    const int NB = (NN + 1023) / 1024;

    // ---- CSR build + preconverts (inputs constant; rebuilt every launch) ----
    hipMemsetAsync(cursor, 0, NN * sizeof(int), stream);
    deg_kernel<<<(NE + 255) / 256, 256, 0, stream>>>(dst, cursor);
    block_sum_kernel<<<NB, 256, 0, stream>>>(cursor, bsum);
    scan_bsum_kernel<<<1, 64, 0, stream>>>(bsum, NB);
    scan_block_kernel<<<NB, 256, 0, stream>>>(cursor, bsum, offsets);
    hipMemsetAsync(cursor, 0, NN * sizeof(int), stream);
    scatter_kernel<<<(NE + 255) / 256, 256, 0, stream>>>(src, dst, offsets, cursor,
                                                         sorted_eid, sorted_src, sorted_dst);
    eperm_kernel<<<(NE * 4 + 255) / 256, 256, 0, stream>>>(e, sorted_eid, eb_s);
    wconv_kernel<<<(L * 32 * 160 + 255) / 256, 256, 0, stream>>>(Wem, Wt);
    hconv_kernel<<<(NN * D + 255) / 256, 256, 0, stream>>>(node_features, h, hb);
    // layer-0 edge bias from sorted bf16 e-state (layers 1,2 biases fused in edge_update)
    ebias0_kernel<<<(NE * H + 255) / 256, 256, 0, stream>>>(eb_s, We, ebias_s);

    for (int layer = 0; layer < L; layer++) {
        const float* Wq_l = Wq + layer * D * D;
        const float* Wk_l = Wk + layer * D * D;
        const float* Wv_l = Wv + layer * D * D;
        const float* Wo_l = Wo + layer * D * D;
        const unsigned short* Wt_l = Wt + layer * 32 * 160;
        const float* bem_l = bem + layer * DE;
        const float* gn_l = gn + layer * D;
        const float* bn_l = bn + layer * D;
        const float* ge_l = ge + layer * DE;
        const float* be_l = be + layer * DE;
        int do_bias = (layer < L - 1);
        const float* We_next = We + (do_bias ? (layer + 1) : layer) * DE * H;

        qkv_kernel<<<NN / 16, dim3(64, 4), 0, stream>>>(h, Wq_l, Wk_l, Wv_l, q, kv);
        attn_kernel<<<NN / 4, dim3(64, 4), 0, stream>>>(q, kv, ebias_s, sorted_src,
                                                        offsets, agg);
        node_update_kernel<<<NN / 16, dim3(64, 4), 0, stream>>>(h, agg, Wo_l,
                                                                gn_l, bn_l, hb);
        edge_update_mfma_kernel<<<NE / 64, 256, 0, stream>>>(hb, eb_s, sorted_src,
                                                             sorted_dst, Wt_l,
                                                             bem_l, ge_l, be_l,
                                                             We_next, ebias_s, do_bias);
    }
}